// Round 1
// baseline (6511.990 us; speedup 1.0000x reference)
//
#include <hip/hip_runtime.h>
#include <cstddef>

#define H 128
#define E_ 30
#define T_ 60
#define DF 6
#define NC 384     // 3*H
#define RT 32      // rows per block in GRU kernel

// ---- workspace layout (float offsets) ----
#define OFF_WT0   0           // Whh0^T  [128][384]
#define OFF_WIT1  49152       // Wih1^T  [128][384]
#define OFF_WHT1  98304       // Whh1^T  [128][384]
#define OFF_WFCT  147456      // Wfc^T   [128][128]
#define OFF_HID   163840      // hidden  [8192][128]
#define OFF_SX    1212416     // sx [8192]
#define OFF_IDV   1220608     // inv_dv [8192]
#define OFF_AGG   1228800     // hidden_agg [30][128]
#define OFF_DE    1232640     // de [30] (pad 32)
#define OFF_S     1232672     // S [30][128]
#define OFF_IDE   1236512     // inv_de [30] (pad 32)
#define OFF_SY    1236544     // sy [30] (pad 32)
#define OFF_CC    1236576     // c1,c2
#define OFF_WV1   1236608     // Wt^T@a1 [128]
#define OFF_WV2   1236736     // Wt^T@a2 [128]
#define ZERO_CNT  7712        // agg+de+S contiguous zero region

#define GRU_LDS_FLOATS (RT*H + RT*H + RT*NC + RT*H + RT*DF)

// ------------------------------------------------------------------ prep
__global__ void k_prep_T(const float* __restrict__ Whh0, const float* __restrict__ Wih1,
                         const float* __restrict__ Whh1, const float* __restrict__ Wfc,
                         float* __restrict__ WT0, float* __restrict__ WiT1,
                         float* __restrict__ WhT1, float* __restrict__ WfcT)
{
    int idx = blockIdx.x * 256 + threadIdx.x;
    if (idx < 3 * NC * H) {
        int m = idx / (NC * H), rem = idx % (NC * H);
        int col = rem / H, k = rem % H;
        const float* src = (m == 0) ? Whh0 : ((m == 1) ? Wih1 : Whh1);
        float* dst = (m == 0) ? WT0 : ((m == 1) ? WiT1 : WhT1);
        dst[k * NC + col] = src[rem];
    } else if (idx < 3 * NC * H + H * H) {
        int i = idx - 3 * NC * H;
        int col = i / H, h = i % H;
        WfcT[h * H + col] = Wfc[i];
    }
}

__global__ void k_prep_wv(const float* __restrict__ Wt, const float* __restrict__ bt,
                          const float* __restrict__ a, float* __restrict__ wv1,
                          float* __restrict__ wv2, float* __restrict__ cc)
{
    int i = threadIdx.x;  // 0..127
    float s1 = 0.f, s2 = 0.f;
    for (int j = 0; j < H; ++j) {
        float w = Wt[(size_t)j * H + i];
        s1 += w * a[j];
        s2 += w * a[H + j];
    }
    wv1[i] = s1;
    wv2[i] = s2;
    if (i == 0) {
        float c1 = 0.f, c2 = 0.f;
        for (int j = 0; j < H; ++j) { c1 += bt[j] * a[j]; c2 += bt[j] * a[H + j]; }
        cc[0] = c1; cc[1] = c2;
    }
}

__global__ void k_zero(float* __restrict__ z)
{
    int i = blockIdx.x * 256 + threadIdx.x;
    if (i < ZERO_CNT) z[i] = 0.f;
}

// ------------------------------------------------------------------ fused 2-layer GRU
// grid 256 blocks (1/CU), 384 threads. Thread c owns output column c of the
// 3H-wide gate pre-activations for all 32 rows; weights read coalesced from
// transposed copies; h tiles broadcast from LDS (wave-uniform addresses).
__global__ __launch_bounds__(384) void k_gru(
    const float* __restrict__ x,
    const float* __restrict__ WT0, const float* __restrict__ WiT1,
    const float* __restrict__ WhT1, const float* __restrict__ Wih0,
    const float* __restrict__ bih0, const float* __restrict__ bhh0,
    const float* __restrict__ bih1, const float* __restrict__ bhh1,
    float* __restrict__ hidden)
{
    extern __shared__ float lds[];
    float* h0 = lds;               // [RT][H]
    float* h1 = h0 + RT * H;       // [RT][H]
    float* gm = h1 + RT * H;       // [RT][NC]  merged gi+gh (gh only for n-cols)
    float* gn = gm + RT * NC;      // [RT][H]   gi of n-gate
    float* xs = gn + RT * H;       // [RT][DF]

    const int tid = threadIdx.x;
    const int n0 = blockIdx.x * RT;
    const int c = tid;
    const bool isN = (c >= 2 * H);

    for (int i = tid; i < RT * H; i += 384) { h0[i] = 0.f; h1[i] = 0.f; }

    const float b0m = isN ? bhh0[c] : (bih0[c] + bhh0[c]);
    const float b1m = isN ? bhh1[c] : (bih1[c] + bhh1[c]);
    const float b0n = isN ? bih0[c] : 0.f;
    const float b1n = isN ? bih1[c] : 0.f;
    float wi0[DF];
#pragma unroll
    for (int d = 0; d < DF; ++d) wi0[d] = Wih0[c * DF + d];

    const int gp = tid >> 7;       // gate row-group (0,1 active)
    const int hc = tid & (H - 1);  // gate hidden column
    float hk0[16], hk1[16];
#pragma unroll
    for (int j = 0; j < 16; ++j) { hk0[j] = 0.f; hk1[j] = 0.f; }

    __syncthreads();

    for (int t = 0; t < T_; ++t) {
        if (tid < RT * DF) {
            int r = tid / DF, d = tid % DF;
            xs[tid] = x[(size_t)(n0 + r) * (T_ * DF) + t * DF + d];
        }
        __syncthreads();

        // ================= layer 0 =================
        float am[RT], an[RT];
#pragma unroll
        for (int r = 0; r < RT; ++r) am[r] = b0m;
#pragma unroll
        for (int r = 0; r < RT; ++r) an[r] = b0n;

        // gi0 (K=6)
#pragma unroll
        for (int d = 0; d < DF; ++d) {
            float w = wi0[d];
            if (!isN) {
#pragma unroll
                for (int r = 0; r < RT; ++r) am[r] += xs[r * DF + d] * w;
            } else {
#pragma unroll
                for (int r = 0; r < RT; ++r) an[r] += xs[r * DF + d] * w;
            }
        }
        // gh0 (K=128)
        for (int k = 0; k < H; k += 4) {
            float w0 = WT0[(k + 0) * NC + c];
            float w1 = WT0[(k + 1) * NC + c];
            float w2 = WT0[(k + 2) * NC + c];
            float w3 = WT0[(k + 3) * NC + c];
#pragma unroll
            for (int r = 0; r < RT; ++r) {
                const float4 hv = *(const float4*)&h0[r * H + k];
                am[r] += hv.x * w0 + hv.y * w1 + hv.z * w2 + hv.w * w3;
            }
        }
#pragma unroll
        for (int r = 0; r < RT; ++r) gm[r * NC + c] = am[r];
        if (isN) {
#pragma unroll
            for (int r = 0; r < RT; ++r) gn[r * H + (c - 2 * H)] = an[r];
        }
        __syncthreads();

        if (gp < 2) {
#pragma unroll
            for (int j = 0; j < 16; ++j) {
                int r = gp * 16 + j;
                float vr  = gm[r * NC + hc];
                float vz  = gm[r * NC + H + hc];
                float vhn = gm[r * NC + 2 * H + hc];
                float vin = gn[r * H + hc];
                float rg = 1.f / (1.f + __expf(-vr));
                float zg = 1.f / (1.f + __expf(-vz));
                float e2 = __expf(2.f * (vin + rg * vhn));
                float ng = 1.f - 2.f / (e2 + 1.f);
                float hn = (1.f - zg) * ng + zg * hk0[j];
                hk0[j] = hn;
                h0[r * H + hc] = hn;
            }
        }
        __syncthreads();

        // ================= layer 1 =================
#pragma unroll
        for (int r = 0; r < RT; ++r) am[r] = b1m;
#pragma unroll
        for (int r = 0; r < RT; ++r) an[r] = b1n;
        for (int k = 0; k < H; k += 4) {
            float wi_0 = WiT1[(k + 0) * NC + c];
            float wi_1 = WiT1[(k + 1) * NC + c];
            float wi_2 = WiT1[(k + 2) * NC + c];
            float wi_3 = WiT1[(k + 3) * NC + c];
            float wh_0 = WhT1[(k + 0) * NC + c];
            float wh_1 = WhT1[(k + 1) * NC + c];
            float wh_2 = WhT1[(k + 2) * NC + c];
            float wh_3 = WhT1[(k + 3) * NC + c];
            if (!isN) {
#pragma unroll
                for (int r = 0; r < RT; ++r) {
                    const float4 yv = *(const float4*)&h0[r * H + k];
                    const float4 hv = *(const float4*)&h1[r * H + k];
                    am[r] += yv.x * wi_0 + yv.y * wi_1 + yv.z * wi_2 + yv.w * wi_3
                           + hv.x * wh_0 + hv.y * wh_1 + hv.z * wh_2 + hv.w * wh_3;
                }
            } else {
#pragma unroll
                for (int r = 0; r < RT; ++r) {
                    const float4 yv = *(const float4*)&h0[r * H + k];
                    const float4 hv = *(const float4*)&h1[r * H + k];
                    an[r] += yv.x * wi_0 + yv.y * wi_1 + yv.z * wi_2 + yv.w * wi_3;
                    am[r] += hv.x * wh_0 + hv.y * wh_1 + hv.z * wh_2 + hv.w * wh_3;
                }
            }
        }
#pragma unroll
        for (int r = 0; r < RT; ++r) gm[r * NC + c] = am[r];
        if (isN) {
#pragma unroll
            for (int r = 0; r < RT; ++r) gn[r * H + (c - 2 * H)] = an[r];
        }
        __syncthreads();

        if (gp < 2) {
#pragma unroll
            for (int j = 0; j < 16; ++j) {
                int r = gp * 16 + j;
                float vr  = gm[r * NC + hc];
                float vz  = gm[r * NC + H + hc];
                float vhn = gm[r * NC + 2 * H + hc];
                float vin = gn[r * H + hc];
                float rg = 1.f / (1.f + __expf(-vr));
                float zg = 1.f / (1.f + __expf(-vz));
                float e2 = __expf(2.f * (vin + rg * vhn));
                float ng = 1.f - 2.f / (e2 + 1.f);
                float hn = (1.f - zg) * ng + zg * hk1[j];
                hk1[j] = hn;
                h1[r * H + hc] = hn;
            }
        }
        __syncthreads();
    }

    if (gp < 2) {
#pragma unroll
        for (int j = 0; j < 16; ++j) {
            int r = gp * 16 + j;
            hidden[(size_t)(n0 + r) * H + hc] = hk1[j];
        }
    }
}

// ------------------------------------------------------------------ epilogue
__global__ void k_rowstats(const float* __restrict__ hidden, const float* __restrict__ GH,
                           const float* __restrict__ wv1, const float* __restrict__ cc,
                           float* __restrict__ sx, float* __restrict__ invdv)
{
    int lane = threadIdx.x & 63;
    int wv = threadIdx.x >> 6;
    int n = blockIdx.x * 4 + wv;
    float p = hidden[(size_t)n * H + lane] * wv1[lane]
            + hidden[(size_t)n * H + 64 + lane] * wv1[64 + lane];
    float g = (lane < E_) ? GH[(size_t)n * E_ + lane] : 0.f;
#pragma unroll
    for (int off = 32; off > 0; off >>= 1) {
        p += __shfl_down(p, off);
        g += __shfl_down(g, off);
    }
    if (lane == 0) {
        sx[n] = p + cc[0];
        float dv = 0.5f * g;
        invdv[n] = (dv != 0.f) ? 1.f / dv : 0.f;
    }
}

__global__ void k_agg(const float* __restrict__ hidden, const float* __restrict__ GH,
                      float* __restrict__ agg, float* __restrict__ de)
{
    int t = threadIdx.x;
    int nbase = blockIdx.x * 128;
    if (t < H) {
        float part[E_];
#pragma unroll
        for (int e = 0; e < E_; ++e) part[e] = 0.f;
        for (int r = 0; r < 128; ++r) {
            int n = nbase + r;
            float hv = hidden[(size_t)n * H + t];
#pragma unroll
            for (int e = 0; e < E_; ++e) part[e] += GH[(size_t)n * E_ + e] * hv;
        }
#pragma unroll
        for (int e = 0; e < E_; ++e) atomicAdd(&agg[e * H + t], part[e]);
    } else if (t < H + E_) {
        int e = t - H;
        float s = 0.f;
        for (int r = 0; r < 128; ++r) s += GH[(size_t)(nbase + r) * E_ + e];
        atomicAdd(&de[e], s);
    }
}

__global__ void k_sy(const float* __restrict__ agg, const float* __restrict__ wv2,
                     const float* __restrict__ cc, const float* __restrict__ de,
                     float* __restrict__ sy, float* __restrict__ invde)
{
    int e = threadIdx.x;
    if (e < E_) {
        float s = 0.f;
        for (int h = 0; h < H; ++h) s += agg[e * H + h] * wv2[h];
        sy[e] = s + cc[1];
        float d = de[e];
        invde[e] = (d != 0.f) ? 1.f / d : 0.f;
    }
}

__global__ void k_attS(const float* __restrict__ hidden, const float* __restrict__ sx,
                       const float* __restrict__ sy, const float* __restrict__ invdv,
                       float* __restrict__ S)
{
    __shared__ float att_s[E_];
    __shared__ float sy_s[E_];
    int t = threadIdx.x;
    if (t < E_) sy_s[t] = sy[t];
    __syncthreads();
    float part[E_];
#pragma unroll
    for (int e = 0; e < E_; ++e) part[e] = 0.f;
    int nbase = blockIdx.x * 128;
    for (int r = 0; r < 128; ++r) {
        int n = nbase + r;
        if (t < 64) {
            float v = -1e30f;
            if (t < E_) {
                v = sx[n] + sy_s[t];
                v = (v >= 0.f) ? v : 0.01f * v;
            }
            float m = v;
#pragma unroll
            for (int off = 32; off > 0; off >>= 1) m = fmaxf(m, __shfl_down(m, off));
            m = __shfl(m, 0);
            float ev = (t < E_) ? __expf(v - m) : 0.f;
            float s = ev;
#pragma unroll
            for (int off = 32; off > 0; off >>= 1) s += __shfl_down(s, off);
            s = __shfl(s, 0);
            if (t < E_) att_s[t] = ev / s;
        }
        __syncthreads();
        if (t < H) {
            float hv = invdv[n] * hidden[(size_t)n * H + t];
#pragma unroll
            for (int e = 0; e < E_; ++e) part[e] += att_s[e] * hv;
        }
        __syncthreads();
    }
    if (t < H) {
#pragma unroll
        for (int e = 0; e < E_; ++e) atomicAdd(&S[e * H + t], part[e]);
    }
}

__global__ void k_final(const float* __restrict__ hidden, const float* __restrict__ sx,
                        const float* __restrict__ sy, const float* __restrict__ invdv,
                        const float* __restrict__ invde, const float* __restrict__ S,
                        const float* __restrict__ WfcT, const float* __restrict__ bfc,
                        const float* __restrict__ Wout, const float* __restrict__ bout,
                        float* __restrict__ out)
{
    __shared__ float S_s[E_ * H];
    __shared__ float sy_s[E_], ide_s[E_];
    __shared__ float newh[2][H];
    __shared__ float red[2][2];
    int t = threadIdx.x;
    for (int i = t; i < E_ * H; i += 256) S_s[i] = S[i];
    if (t < E_) { sy_s[t] = sy[t]; ide_s[t] = invde[t]; }
    __syncthreads();
    int slot = t >> 7, hc = t & (H - 1);
    float wout_c = Wout[hc];
    float bfc_c = bfc[hc];
    float boutv = bout[0];
    for (int it = 0; it < 32; ++it) {
        int n = blockIdx.x * 64 + it * 2 + slot;
        float sxn = sx[n];
        float idv = invdv[n];
        float vv[E_];
        float m = -1e30f;
#pragma unroll
        for (int e = 0; e < E_; ++e) {
            float v = sxn + sy_s[e];
            v = (v >= 0.f) ? v : 0.01f * v;
            vv[e] = v;
            m = fmaxf(m, v);
        }
        float ssum = 0.f;
#pragma unroll
        for (int e = 0; e < E_; ++e) { vv[e] = __expf(vv[e] - m); ssum += vv[e]; }
        float sc = idv / ssum;
        float acc = hidden[(size_t)n * H + hc];
#pragma unroll
        for (int e = 0; e < E_; ++e) acc += vv[e] * sc * ide_s[e] * S_s[e * H + hc];
        newh[slot][hc] = acc;
        __syncthreads();
        float f = bfc_c;
        for (int h = 0; h < H; ++h) f += newh[slot][h] * WfcT[h * H + hc];
        f = (f >= 0.f) ? f : 0.01f * f;
        float op = f * wout_c;
#pragma unroll
        for (int off = 32; off > 0; off >>= 1) op += __shfl_down(op, off);
        if ((t & 63) == 0) red[slot][(t >> 6) & 1] = op;
        __syncthreads();
        if (hc == 0) out[n] = red[slot][0] + red[slot][1] + boutv;
        __syncthreads();
    }
}

// ------------------------------------------------------------------ launcher
extern "C" void kernel_launch(void* const* d_in, const int* in_sizes, int n_in,
                              void* d_out, int out_size, void* d_ws, size_t ws_size,
                              hipStream_t stream)
{
    const float* x    = (const float*)d_in[0];
    const float* GH   = (const float*)d_in[1];
    const float* Wih0 = (const float*)d_in[2];
    const float* Whh0 = (const float*)d_in[3];
    const float* bih0 = (const float*)d_in[4];
    const float* bhh0 = (const float*)d_in[5];
    const float* Wih1 = (const float*)d_in[6];
    const float* Whh1 = (const float*)d_in[7];
    const float* bih1 = (const float*)d_in[8];
    const float* bhh1 = (const float*)d_in[9];
    const float* Wt   = (const float*)d_in[10];
    const float* bt   = (const float*)d_in[11];
    const float* a    = (const float*)d_in[12];
    const float* Wfc  = (const float*)d_in[13];
    const float* bfc  = (const float*)d_in[14];
    const float* Wout = (const float*)d_in[15];
    const float* bout = (const float*)d_in[16];

    float* ws   = (float*)d_ws;
    float* WT0  = ws + OFF_WT0;
    float* WiT1 = ws + OFF_WIT1;
    float* WhT1 = ws + OFF_WHT1;
    float* WfcT = ws + OFF_WFCT;
    float* hid  = ws + OFF_HID;
    float* sx   = ws + OFF_SX;
    float* idv  = ws + OFF_IDV;
    float* agg  = ws + OFF_AGG;
    float* de   = ws + OFF_DE;
    float* S    = ws + OFF_S;
    float* ide  = ws + OFF_IDE;
    float* sy   = ws + OFF_SY;
    float* cc   = ws + OFF_CC;
    float* wv1  = ws + OFF_WV1;
    float* wv2  = ws + OFF_WV2;

    k_prep_T<<<640, 256, 0, stream>>>(Whh0, Wih1, Whh1, Wfc, WT0, WiT1, WhT1, WfcT);
    k_prep_wv<<<1, 128, 0, stream>>>(Wt, bt, a, wv1, wv2, cc);
    k_zero<<<31, 256, 0, stream>>>(agg);

    const size_t lds_bytes = GRU_LDS_FLOATS * sizeof(float);  // 99072 B
    (void)hipFuncSetAttribute((const void*)k_gru,
                              hipFuncAttributeMaxDynamicSharedMemorySize,
                              (int)lds_bytes);
    k_gru<<<256, 384, lds_bytes, stream>>>(x, WT0, WiT1, WhT1, Wih0,
                                           bih0, bhh0, bih1, bhh1, hid);

    k_rowstats<<<2048, 256, 0, stream>>>(hid, GH, wv1, cc, sx, idv);
    k_agg<<<64, 256, 0, stream>>>(hid, GH, agg, de);
    k_sy<<<1, 64, 0, stream>>>(agg, wv2, cc, de, sy, ide);
    k_attS<<<64, 256, 0, stream>>>(hid, sx, sy, idv, S);
    k_final<<<128, 256, 0, stream>>>(hid, sx, sy, idv, ide, S, WfcT, bfc,
                                     Wout, bout, (float*)d_out);
}

// Round 2
// 2746.848 us; speedup vs baseline: 2.3707x; 2.3707x over previous
//
#include <hip/hip_runtime.h>
#include <cstddef>

#define H 128
#define E_ 30
#define T_ 60
#define DF 6

typedef unsigned int u32;
typedef __attribute__((ext_vector_type(8))) short short8;
typedef __attribute__((ext_vector_type(4))) float f32x4;

// ---- workspace layout (float offsets) ----
#define OFF_PACKHI 0          // uint4[8*39*64]
#define OFF_PACKLO 79872
#define OFF_WFCT   159744     // Wfc^T [128][128]
#define OFF_HID    176128     // hidden [8192][128]
#define OFF_SX     1224704
#define OFF_IDV    1232896
#define OFF_AGG    1241088
#define OFF_DE     1244928
#define OFF_S      1244960
#define OFF_IDE    1248800
#define OFF_SY     1248832
#define OFF_CC     1248864
#define OFF_WV1    1248896
#define OFF_WV2    1249024
#define ZERO_CNT   7712

__device__ __forceinline__ unsigned short f2bf(float f) {
    u32 x = __float_as_uint(f);
    u32 r = (x + 0x7fffu + ((x >> 16) & 1u)) >> 16;
    return (unsigned short)r;
}
__device__ __forceinline__ float bf2f(unsigned short h) {
    return __uint_as_float(((u32)h) << 16);
}

// ------------------------------------------------------------------ weight packing
// B-fragment order for mfma_f32_16x16x32_bf16: lane l holds B[k][c] with
// c = hc0 + (l&15), k = kt*32 + 8*(l>>4) + i  (8 consecutive k per lane).
// Slots per hc-group j (39 total):
//  L0: s0-4 r (K=160: h0|x|pad), s5-9 z, s10-13 ghn (K=128), s14 gin (x, Kpad32)
//  L1: s15-22 r (K=256: y|h1), s23-30 z, s31-34 ghn (h1), s35-38 gin (y)
__global__ void k_pack(const float* __restrict__ Wih0, const float* __restrict__ Whh0,
                       const float* __restrict__ Wih1, const float* __restrict__ Whh1,
                       uint4* __restrict__ packhi, uint4* __restrict__ packlo)
{
    int u = blockIdx.x * 256 + threadIdx.x;   // 78*256 = 19968 exact
    int lane = u & 63;
    int s = (u >> 6) % 39;
    int j = (u >> 6) / 39;
    int hc = j * 16 + (lane & 15);
    int g = lane >> 4;
    int layer, gate, kt;
    if (s < 5)       { layer = 0; gate = 0; kt = s; }
    else if (s < 10) { layer = 0; gate = 1; kt = s - 5; }
    else if (s < 14) { layer = 0; gate = 2; kt = s - 10; }
    else if (s < 15) { layer = 0; gate = 3; kt = 0; }
    else if (s < 23) { layer = 1; gate = 0; kt = s - 15; }
    else if (s < 31) { layer = 1; gate = 1; kt = s - 23; }
    else if (s < 35) { layer = 1; gate = 2; kt = s - 31; }
    else             { layer = 1; gate = 3; kt = s - 35; }

    u32 hiw[4], low[4];
    for (int p = 0; p < 4; ++p) {
        unsigned short hh[2], ll[2];
        for (int q = 0; q < 2; ++q) {
            int k = kt * 32 + g * 8 + p * 2 + q;
            float v = 0.f;
            if (layer == 0) {
                if (gate <= 1) {
                    int row = gate * 128 + hc;
                    if (k < 128) v = Whh0[row * 128 + k];
                    else if (k < 134) v = Wih0[row * 6 + (k - 128)];
                } else if (gate == 2) {
                    v = Whh0[(256 + hc) * 128 + k];
                } else {
                    if (k < 6) v = Wih0[(256 + hc) * 6 + k];
                }
            } else {
                if (gate <= 1) {
                    int row = gate * 128 + hc;
                    v = (k < 128) ? Wih1[row * 128 + k] : Whh1[row * 128 + (k - 128)];
                } else if (gate == 2) {
                    v = Whh1[(256 + hc) * 128 + k];
                } else {
                    v = Wih1[(256 + hc) * 128 + k];
                }
            }
            unsigned short hb = f2bf(v);
            hh[q] = hb;
            ll[q] = f2bf(v - bf2f(hb));
        }
        hiw[p] = (u32)hh[0] | ((u32)hh[1] << 16);
        low[p] = (u32)ll[0] | ((u32)ll[1] << 16);
    }
    int idx = (j * 39 + s) * 64 + lane;
    packhi[idx] = make_uint4(hiw[0], hiw[1], hiw[2], hiw[3]);
    packlo[idx] = make_uint4(low[0], low[1], low[2], low[3]);
}

__global__ void k_prep_fc(const float* __restrict__ Wfc, float* __restrict__ WfcT)
{
    int i = blockIdx.x * 256 + threadIdx.x;   // 64*256 = 16384
    int col = i / 128, h = i % 128;
    WfcT[h * 128 + col] = Wfc[i];
}

__global__ void k_prep_wv(const float* __restrict__ Wt, const float* __restrict__ bt,
                          const float* __restrict__ a, float* __restrict__ wv1,
                          float* __restrict__ wv2, float* __restrict__ cc)
{
    int i = threadIdx.x;  // 0..127
    float s1 = 0.f, s2 = 0.f;
    for (int j = 0; j < H; ++j) {
        float w = Wt[(size_t)j * H + i];
        s1 += w * a[j];
        s2 += w * a[H + j];
    }
    wv1[i] = s1;
    wv2[i] = s2;
    if (i == 0) {
        float c1 = 0.f, c2 = 0.f;
        for (int j = 0; j < H; ++j) { c1 += bt[j] * a[j]; c2 += bt[j] * a[H + j]; }
        cc[0] = c1; cc[1] = c2;
    }
}

__global__ void k_zero(float* __restrict__ z)
{
    int i = blockIdx.x * 256 + threadIdx.x;
    if (i < ZERO_CNT) z[i] = 0.f;
}

// ------------------------------------------------------------------ fused 2-layer GRU (MFMA)
// 256 blocks x 1024 threads (16 waves/CU). Wave w: rows r0=(w&1)*16, hidden
// cols hc0=(w>>1)*16. All 4 gate tiles per wave -> activations in registers.
// Weights register-resident (hi/lo bf16 split, 2 MFMA per K-tile).
// h0/h1 double-buffered bf16 in LDS, XOR-swizzled (chunk ^= row&15).
#define MFMA __builtin_amdgcn_mfma_f32_16x16x32_bf16

__global__ __launch_bounds__(1024, 4) void k_gru(
    const float* __restrict__ x,
    const uint4* __restrict__ packhi, const uint4* __restrict__ packlo,
    const float* __restrict__ bih0, const float* __restrict__ bhh0,
    const float* __restrict__ bih1, const float* __restrict__ bhh1,
    float* __restrict__ hidden)
{
    extern __shared__ char smem[];
    // [0,16384): h0[2][32][128]bf16  [16384,32768): h1[2]  [32768,65024): x[63][32]x16B
    const int tid = threadIdx.x;
    const int lane = tid & 63;
    const int w = tid >> 6;
    const int r0 = (w & 1) << 4;
    const int j = w >> 1;
    const int xr = lane & 15;
    const int g = lane >> 4;
    const int R = r0 + xr;              // A-fragment row
    const int hc = (j << 4) + xr;       // D-fragment col (hidden unit)
    const int n0 = blockIdx.x << 5;

    // x preload: cell (r,t) = 6 bf16 + 2 zero pads, at 32768 + t*512 + r*16
    for (int c = tid; c < 32 * 60; c += 1024) {
        int r = c / 60, t = c % 60;
        const float* xp = x + (size_t)(n0 + r) * (T_ * DF) + t * DF;
        u32 w0 = (u32)f2bf(xp[0]) | ((u32)f2bf(xp[1]) << 16);
        u32 w1 = (u32)f2bf(xp[2]) | ((u32)f2bf(xp[3]) << 16);
        u32 w2 = (u32)f2bf(xp[4]) | ((u32)f2bf(xp[5]) << 16);
        *(uint4*)(smem + 32768 + t * 512 + r * 16) = make_uint4(w0, w1, w2, 0u);
    }
    // zero x pad rows 60..62 (NaN-safe garbage-k reads) and h buffers [0]
    for (int i = tid; i < 384; i += 1024) ((u32*)(smem + 32768 + 30720))[i] = 0u;
    for (int i = tid; i < 2048; i += 1024) {
        ((u32*)smem)[i] = 0u;
        ((u32*)(smem + 16384))[i] = 0u;
    }

    uint4 whi[39], wlo[39];
#pragma unroll
    for (int s = 0; s < 39; ++s) {
        int idx = ((j * 39 + s) << 6) + lane;
        whi[s] = packhi[idx];
        wlo[s] = packlo[idx];
    }

    const float br0 = bih0[hc] + bhh0[hc];
    const float bz0 = bih0[H + hc] + bhh0[H + hc];
    const float bgn0 = bhh0[2 * H + hc];
    const float bgi0 = bih0[2 * H + hc];
    const float br1 = bih1[hc] + bhh1[hc];
    const float bz1 = bih1[H + hc] + bhh1[H + hc];
    const float bgn1 = bhh1[2 * H + hc];
    const float bgi1 = bih1[2 * H + hc];

    float hs0[4] = {0.f, 0.f, 0.f, 0.f};
    float hs1[4] = {0.f, 0.f, 0.f, 0.f};

    __syncthreads();

    for (int t = 0; t < T_; ++t) {
        const int cur = (t & 1) << 13;   // 0 / 8192 byte offset
        const int nxt = cur ^ 8192;

        // ================= layer 0 =================
        uint4 a[5];
#pragma unroll
        for (int kt = 0; kt < 4; ++kt)
            a[kt] = *(const uint4*)(smem + cur + (R << 8) + ((((kt << 2) | g) ^ xr) << 4));
        a[4] = *(const uint4*)(smem + 32768 + ((t + g) << 9) + (R << 4));

        f32x4 aR = {0,0,0,0}, aZ = {0,0,0,0}, aG = {0,0,0,0}, aI = {0,0,0,0};
#pragma unroll
        for (int kt = 0; kt < 5; ++kt) {
            short8 av = __builtin_bit_cast(short8, a[kt]);
            aR = MFMA(av, __builtin_bit_cast(short8, whi[kt]), aR, 0, 0, 0);
            aR = MFMA(av, __builtin_bit_cast(short8, wlo[kt]), aR, 0, 0, 0);
            aZ = MFMA(av, __builtin_bit_cast(short8, whi[5 + kt]), aZ, 0, 0, 0);
            aZ = MFMA(av, __builtin_bit_cast(short8, wlo[5 + kt]), aZ, 0, 0, 0);
        }
#pragma unroll
        for (int kt = 0; kt < 4; ++kt) {
            short8 av = __builtin_bit_cast(short8, a[kt]);
            aG = MFMA(av, __builtin_bit_cast(short8, whi[10 + kt]), aG, 0, 0, 0);
            aG = MFMA(av, __builtin_bit_cast(short8, wlo[10 + kt]), aG, 0, 0, 0);
        }
        {
            short8 av = __builtin_bit_cast(short8, a[4]);
            aI = MFMA(av, __builtin_bit_cast(short8, whi[14]), aI, 0, 0, 0);
            aI = MFMA(av, __builtin_bit_cast(short8, wlo[14]), aI, 0, 0, 0);
        }
#pragma unroll
        for (int i = 0; i < 4; ++i) {
            float rg = 1.f / (1.f + __expf(-(aR[i] + br0)));
            float zg = 1.f / (1.f + __expf(-(aZ[i] + bz0)));
            float nn = aI[i] + bgi0 + rg * (aG[i] + bgn0);
            float e2 = __expf(2.f * nn);
            float ng = 1.f - 2.f / (e2 + 1.f);
            float hn = ng + zg * (hs0[i] - ng);
            hs0[i] = hn;
            int Rw = r0 + (g << 2) + i;
            *(unsigned short*)(smem + nxt + (Rw << 8) + (((hc >> 3) ^ (Rw & 15)) << 4) + ((hc & 7) << 1)) = f2bf(hn);
        }
        __syncthreads();

        // ================= layer 1 =================
        uint4 b[8];
#pragma unroll
        for (int kt = 0; kt < 4; ++kt)
            b[kt] = *(const uint4*)(smem + nxt + (R << 8) + ((((kt << 2) | g) ^ xr) << 4));
#pragma unroll
        for (int kt = 0; kt < 4; ++kt)
            b[4 + kt] = *(const uint4*)(smem + 16384 + cur + (R << 8) + ((((kt << 2) | g) ^ xr) << 4));

        f32x4 cR = {0,0,0,0}, cZ = {0,0,0,0}, cG = {0,0,0,0}, cI = {0,0,0,0};
#pragma unroll
        for (int kt = 0; kt < 8; ++kt) {
            short8 bv = __builtin_bit_cast(short8, b[kt]);
            cR = MFMA(bv, __builtin_bit_cast(short8, whi[15 + kt]), cR, 0, 0, 0);
            cR = MFMA(bv, __builtin_bit_cast(short8, wlo[15 + kt]), cR, 0, 0, 0);
            cZ = MFMA(bv, __builtin_bit_cast(short8, whi[23 + kt]), cZ, 0, 0, 0);
            cZ = MFMA(bv, __builtin_bit_cast(short8, wlo[23 + kt]), cZ, 0, 0, 0);
        }
#pragma unroll
        for (int kt = 0; kt < 4; ++kt) {
            short8 bv = __builtin_bit_cast(short8, b[4 + kt]);
            cG = MFMA(bv, __builtin_bit_cast(short8, whi[31 + kt]), cG, 0, 0, 0);
            cG = MFMA(bv, __builtin_bit_cast(short8, wlo[31 + kt]), cG, 0, 0, 0);
        }
#pragma unroll
        for (int kt = 0; kt < 4; ++kt) {
            short8 bv = __builtin_bit_cast(short8, b[kt]);
            cI = MFMA(bv, __builtin_bit_cast(short8, whi[35 + kt]), cI, 0, 0, 0);
            cI = MFMA(bv, __builtin_bit_cast(short8, wlo[35 + kt]), cI, 0, 0, 0);
        }
#pragma unroll
        for (int i = 0; i < 4; ++i) {
            float rg = 1.f / (1.f + __expf(-(cR[i] + br1)));
            float zg = 1.f / (1.f + __expf(-(cZ[i] + bz1)));
            float nn = cI[i] + bgi1 + rg * (cG[i] + bgn1);
            float e2 = __expf(2.f * nn);
            float ng = 1.f - 2.f / (e2 + 1.f);
            float hn = ng + zg * (hs1[i] - ng);
            hs1[i] = hn;
            int Rw = r0 + (g << 2) + i;
            *(unsigned short*)(smem + 16384 + nxt + (Rw << 8) + (((hc >> 3) ^ (Rw & 15)) << 4) + ((hc & 7) << 1)) = f2bf(hn);
        }
        __syncthreads();
    }

#pragma unroll
    for (int i = 0; i < 4; ++i) {
        int Rw = r0 + (g << 2) + i;
        hidden[(size_t)(n0 + Rw) * H + hc] = hs1[i];
    }
}

// ------------------------------------------------------------------ epilogue (unchanged from R1)
__global__ void k_rowstats(const float* __restrict__ hidden, const float* __restrict__ GH,
                           const float* __restrict__ wv1, const float* __restrict__ cc,
                           float* __restrict__ sx, float* __restrict__ invdv)
{
    int lane = threadIdx.x & 63;
    int wv = threadIdx.x >> 6;
    int n = blockIdx.x * 4 + wv;
    float p = hidden[(size_t)n * H + lane] * wv1[lane]
            + hidden[(size_t)n * H + 64 + lane] * wv1[64 + lane];
    float g = (lane < E_) ? GH[(size_t)n * E_ + lane] : 0.f;
#pragma unroll
    for (int off = 32; off > 0; off >>= 1) {
        p += __shfl_down(p, off);
        g += __shfl_down(g, off);
    }
    if (lane == 0) {
        sx[n] = p + cc[0];
        float dv = 0.5f * g;
        invdv[n] = (dv != 0.f) ? 1.f / dv : 0.f;
    }
}

__global__ void k_agg(const float* __restrict__ hidden, const float* __restrict__ GH,
                      float* __restrict__ agg, float* __restrict__ de)
{
    int t = threadIdx.x;
    int nbase = blockIdx.x * 128;
    if (t < H) {
        float part[E_];
#pragma unroll
        for (int e = 0; e < E_; ++e) part[e] = 0.f;
        for (int r = 0; r < 128; ++r) {
            int n = nbase + r;
            float hv = hidden[(size_t)n * H + t];
#pragma unroll
            for (int e = 0; e < E_; ++e) part[e] += GH[(size_t)n * E_ + e] * hv;
        }
#pragma unroll
        for (int e = 0; e < E_; ++e) atomicAdd(&agg[e * H + t], part[e]);
    } else if (t < H + E_) {
        int e = t - H;
        float s = 0.f;
        for (int r = 0; r < 128; ++r) s += GH[(size_t)(nbase + r) * E_ + e];
        atomicAdd(&de[e], s);
    }
}

__global__ void k_sy(const float* __restrict__ agg, const float* __restrict__ wv2,
                     const float* __restrict__ cc, const float* __restrict__ de,
                     float* __restrict__ sy, float* __restrict__ invde)
{
    int e = threadIdx.x;
    if (e < E_) {
        float s = 0.f;
        for (int h = 0; h < H; ++h) s += agg[e * H + h] * wv2[h];
        sy[e] = s + cc[1];
        float d = de[e];
        invde[e] = (d != 0.f) ? 1.f / d : 0.f;
    }
}

__global__ void k_attS(const float* __restrict__ hidden, const float* __restrict__ sx,
                       const float* __restrict__ sy, const float* __restrict__ invdv,
                       float* __restrict__ S)
{
    __shared__ float att_s[E_];
    __shared__ float sy_s[E_];
    int t = threadIdx.x;
    if (t < E_) sy_s[t] = sy[t];
    __syncthreads();
    float part[E_];
#pragma unroll
    for (int e = 0; e < E_; ++e) part[e] = 0.f;
    int nbase = blockIdx.x * 128;
    for (int r = 0; r < 128; ++r) {
        int n = nbase + r;
        if (t < 64) {
            float v = -1e30f;
            if (t < E_) {
                v = sx[n] + sy_s[t];
                v = (v >= 0.f) ? v : 0.01f * v;
            }
            float m = v;
#pragma unroll
            for (int off = 32; off > 0; off >>= 1) m = fmaxf(m, __shfl_down(m, off));
            m = __shfl(m, 0);
            float ev = (t < E_) ? __expf(v - m) : 0.f;
            float s = ev;
#pragma unroll
            for (int off = 32; off > 0; off >>= 1) s += __shfl_down(s, off);
            s = __shfl(s, 0);
            if (t < E_) att_s[t] = ev / s;
        }
        __syncthreads();
        if (t < H) {
            float hv = invdv[n] * hidden[(size_t)n * H + t];
#pragma unroll
            for (int e = 0; e < E_; ++e) part[e] += att_s[e] * hv;
        }
        __syncthreads();
    }
    if (t < H) {
#pragma unroll
        for (int e = 0; e < E_; ++e) atomicAdd(&S[e * H + t], part[e]);
    }
}

__global__ void k_final(const float* __restrict__ hidden, const float* __restrict__ sx,
                        const float* __restrict__ sy, const float* __restrict__ invdv,
                        const float* __restrict__ invde, const float* __restrict__ S,
                        const float* __restrict__ WfcT, const float* __restrict__ bfc,
                        const float* __restrict__ Wout, const float* __restrict__ bout,
                        float* __restrict__ out)
{
    __shared__ float S_s[E_ * H];
    __shared__ float sy_s[E_], ide_s[E_];
    __shared__ float newh[2][H];
    __shared__ float red[2][2];
    int t = threadIdx.x;
    for (int i = t; i < E_ * H; i += 256) S_s[i] = S[i];
    if (t < E_) { sy_s[t] = sy[t]; ide_s[t] = invde[t]; }
    __syncthreads();
    int slot = t >> 7, hcc = t & (H - 1);
    float wout_c = Wout[hcc];
    float bfc_c = bfc[hcc];
    float boutv = bout[0];
    for (int it = 0; it < 32; ++it) {
        int n = blockIdx.x * 64 + it * 2 + slot;
        float sxn = sx[n];
        float idv = invdv[n];
        float vv[E_];
        float m = -1e30f;
#pragma unroll
        for (int e = 0; e < E_; ++e) {
            float v = sxn + sy_s[e];
            v = (v >= 0.f) ? v : 0.01f * v;
            vv[e] = v;
            m = fmaxf(m, v);
        }
        float ssum = 0.f;
#pragma unroll
        for (int e = 0; e < E_; ++e) { vv[e] = __expf(vv[e] - m); ssum += vv[e]; }
        float sc = idv / ssum;
        float acc = hidden[(size_t)n * H + hcc];
#pragma unroll
        for (int e = 0; e < E_; ++e) acc += vv[e] * sc * ide_s[e] * S_s[e * H + hcc];
        newh[slot][hcc] = acc;
        __syncthreads();
        float f = bfc_c;
        for (int h = 0; h < H; ++h) f += newh[slot][h] * WfcT[h * H + hcc];
        f = (f >= 0.f) ? f : 0.01f * f;
        float op = f * wout_c;
#pragma unroll
        for (int off = 32; off > 0; off >>= 1) op += __shfl_down(op, off);
        if ((t & 63) == 0) red[slot][(t >> 6) & 1] = op;
        __syncthreads();
        if (hcc == 0) out[n] = red[slot][0] + red[slot][1] + boutv;
        __syncthreads();
    }
}

// ------------------------------------------------------------------ launcher
extern "C" void kernel_launch(void* const* d_in, const int* in_sizes, int n_in,
                              void* d_out, int out_size, void* d_ws, size_t ws_size,
                              hipStream_t stream)
{
    const float* x    = (const float*)d_in[0];
    const float* GH   = (const float*)d_in[1];
    const float* Wih0 = (const float*)d_in[2];
    const float* Whh0 = (const float*)d_in[3];
    const float* bih0 = (const float*)d_in[4];
    const float* bhh0 = (const float*)d_in[5];
    const float* Wih1 = (const float*)d_in[6];
    const float* Whh1 = (const float*)d_in[7];
    const float* bih1 = (const float*)d_in[8];
    const float* bhh1 = (const float*)d_in[9];
    const float* Wt   = (const float*)d_in[10];
    const float* bt   = (const float*)d_in[11];
    const float* a    = (const float*)d_in[12];
    const float* Wfc  = (const float*)d_in[13];
    const float* bfc  = (const float*)d_in[14];
    const float* Wout = (const float*)d_in[15];
    const float* bout = (const float*)d_in[16];

    float* ws    = (float*)d_ws;
    uint4* phi   = (uint4*)(ws + OFF_PACKHI);
    uint4* plo   = (uint4*)(ws + OFF_PACKLO);
    float* WfcT  = ws + OFF_WFCT;
    float* hid   = ws + OFF_HID;
    float* sx    = ws + OFF_SX;
    float* idv   = ws + OFF_IDV;
    float* agg   = ws + OFF_AGG;
    float* de    = ws + OFF_DE;
    float* S     = ws + OFF_S;
    float* ide   = ws + OFF_IDE;
    float* sy    = ws + OFF_SY;
    float* cc    = ws + OFF_CC;
    float* wv1   = ws + OFF_WV1;
    float* wv2   = ws + OFF_WV2;

    k_pack<<<78, 256, 0, stream>>>(Wih0, Whh0, Wih1, Whh1, phi, plo);
    k_prep_fc<<<64, 256, 0, stream>>>(Wfc, WfcT);
    k_prep_wv<<<1, 128, 0, stream>>>(Wt, bt, a, wv1, wv2, cc);
    k_zero<<<31, 256, 0, stream>>>(agg);

    const size_t lds_bytes = 65024;
    (void)hipFuncSetAttribute((const void*)k_gru,
                              hipFuncAttributeMaxDynamicSharedMemorySize,
                              (int)lds_bytes);
    k_gru<<<256, 1024, lds_bytes, stream>>>(x, phi, plo, bih0, bhh0, bih1, bhh1, hid);

    k_rowstats<<<2048, 256, 0, stream>>>(hid, GH, wv1, cc, sx, idv);
    k_agg<<<64, 256, 0, stream>>>(hid, GH, agg, de);
    k_sy<<<1, 64, 0, stream>>>(agg, wv2, cc, de, sy, ide);
    k_attS<<<64, 256, 0, stream>>>(hid, sx, sy, idv, S);
    k_final<<<128, 256, 0, stream>>>(hid, sx, sy, idv, ide, S, WfcT, bfc,
                                     Wout, bout, (float*)d_out);
}

// Round 3
// 520.207 us; speedup vs baseline: 12.5181x; 5.2803x over previous
//
#include <hip/hip_runtime.h>
#include <hip/hip_fp16.h>
#include <cstddef>

#define H 128
#define E_ 30
#define T_ 60
#define DF 6

typedef unsigned int u32;
typedef __attribute__((ext_vector_type(8))) short short8;
typedef __attribute__((ext_vector_type(4))) float f32x4;

// ---- workspace layout (float offsets) ----
#define OFF_PACK   0          // uint4[8*39*64] fp16 weights
#define OFF_WFCT   79872      // Wfc^T [128][128]
#define OFF_HID    96256      // hidden [8192][128]
#define OFF_SX     1144832
#define OFF_IDV    1153024
#define OFF_AGG    1161216
#define OFF_DE     1165056
#define OFF_S      1165088
#define OFF_IDE    1168928
#define OFF_SY     1168960
#define OFF_CC     1168992
#define OFF_WV1    1169024
#define OFF_WV2    1169152
#define ZERO_CNT   7712       // agg+de+S contiguous

__device__ __forceinline__ unsigned short f2h(float f) {
    return __half_as_ushort(__float2half(f));
}

// ------------------------------------------------------------------ weight packing (fp16)
// B-fragment order for mfma_f32_16x16x32_f16: lane l holds B[k][c] with
// c = hc0 + (l&15), k = kt*32 + 8*(l>>4) + i  (8 consecutive k per lane).
// Slots per hc-group j (39 total):
//  L0: s0-4 r (K=160: h0|x|pad), s5-9 z, s10-13 ghn (K=128), s14 gin (x, Kpad32)
//  L1: s15-22 r (K=256: y|h1), s23-30 z, s31-34 ghn (h1), s35-38 gin (y)
__global__ void k_pack(const float* __restrict__ Wih0, const float* __restrict__ Whh0,
                       const float* __restrict__ Wih1, const float* __restrict__ Whh1,
                       uint4* __restrict__ pack)
{
    int u = blockIdx.x * 256 + threadIdx.x;   // 78*256 = 19968 exact
    int lane = u & 63;
    int s = (u >> 6) % 39;
    int j = (u >> 6) / 39;
    int hc = j * 16 + (lane & 15);
    int g = lane >> 4;
    int layer, gate, kt;
    if (s < 5)       { layer = 0; gate = 0; kt = s; }
    else if (s < 10) { layer = 0; gate = 1; kt = s - 5; }
    else if (s < 14) { layer = 0; gate = 2; kt = s - 10; }
    else if (s < 15) { layer = 0; gate = 3; kt = 0; }
    else if (s < 23) { layer = 1; gate = 0; kt = s - 15; }
    else if (s < 31) { layer = 1; gate = 1; kt = s - 23; }
    else if (s < 35) { layer = 1; gate = 2; kt = s - 31; }
    else             { layer = 1; gate = 3; kt = s - 35; }

    u32 wd[4];
    for (int p = 0; p < 4; ++p) {
        unsigned short hh[2];
        for (int q = 0; q < 2; ++q) {
            int k = kt * 32 + g * 8 + p * 2 + q;
            float v = 0.f;
            if (layer == 0) {
                if (gate <= 1) {
                    int row = gate * 128 + hc;
                    if (k < 128) v = Whh0[row * 128 + k];
                    else if (k < 134) v = Wih0[row * 6 + (k - 128)];
                } else if (gate == 2) {
                    v = Whh0[(256 + hc) * 128 + k];
                } else {
                    if (k < 6) v = Wih0[(256 + hc) * 6 + k];
                }
            } else {
                if (gate <= 1) {
                    int row = gate * 128 + hc;
                    v = (k < 128) ? Wih1[row * 128 + k] : Whh1[row * 128 + (k - 128)];
                } else if (gate == 2) {
                    v = Whh1[(256 + hc) * 128 + k];
                } else {
                    v = Wih1[(256 + hc) * 128 + k];
                }
            }
            hh[q] = f2h(v);
        }
        wd[p] = (u32)hh[0] | ((u32)hh[1] << 16);
    }
    pack[(j * 39 + s) * 64 + lane] = make_uint4(wd[0], wd[1], wd[2], wd[3]);
}

__global__ void k_prep_fc(const float* __restrict__ Wfc, float* __restrict__ WfcT)
{
    int i = blockIdx.x * 256 + threadIdx.x;   // 64*256 = 16384
    int col = i / 128, h = i % 128;
    WfcT[h * 128 + col] = Wfc[i];
}

__global__ void k_prep_wv(const float* __restrict__ Wt, const float* __restrict__ bt,
                          const float* __restrict__ a, float* __restrict__ wv1,
                          float* __restrict__ wv2, float* __restrict__ cc)
{
    int i = threadIdx.x;  // 0..127
    float s1 = 0.f, s2 = 0.f;
    for (int j = 0; j < H; ++j) {
        float w = Wt[(size_t)j * H + i];
        s1 += w * a[j];
        s2 += w * a[H + j];
    }
    wv1[i] = s1;
    wv2[i] = s2;
    if (i == 0) {
        float c1 = 0.f, c2 = 0.f;
        for (int j = 0; j < H; ++j) { c1 += bt[j] * a[j]; c2 += bt[j] * a[H + j]; }
        cc[0] = c1; cc[1] = c2;
    }
}

__global__ void k_zero(float* __restrict__ z)
{
    int i = blockIdx.x * 256 + threadIdx.x;
    if (i < ZERO_CNT) z[i] = 0.f;
}

// ------------------------------------------------------------------ fused 2-layer GRU (MFMA fp16)
// 256 blocks x 512 threads (8 waves = 2/SIMD -> 256-reg cap). Wave = hidden
// col group j; covers both 16-row tiles. All 4 gate tiles per wave ->
// activations in registers. fp16 weights register-resident (39 uint4 = 156 v).
// h0/h1 double-buffered fp16 in LDS, XOR-swizzled (chunk ^= row&15).
#define MFMA16 __builtin_amdgcn_mfma_f32_16x16x32_f16

__global__ __launch_bounds__(512, 2) void k_gru(
    const float* __restrict__ x,
    const uint4* __restrict__ pack,
    const float* __restrict__ bih0, const float* __restrict__ bhh0,
    const float* __restrict__ bih1, const float* __restrict__ bhh1,
    float* __restrict__ hidden)
{
    extern __shared__ char smem[];
    // [0,16384): h0[2][32][128]f16  [16384,32768): h1[2]  [32768,65024): x[63][32]x16B
    const int tid = threadIdx.x;
    const int lane = tid & 63;
    const int j = tid >> 6;             // wave index = hidden col group
    const int xr = lane & 15;
    const int g = lane >> 4;
    const int hc = (j << 4) + xr;       // D-fragment col (hidden unit)
    const int n0 = blockIdx.x << 5;

    // x preload: cell (r,t) = 6 fp16 + 2 zero pads, at 32768 + t*512 + r*16
    for (int c = tid; c < 32 * 60; c += 512) {
        int r = c / 60, t = c % 60;
        const float* xp = x + (size_t)(n0 + r) * (T_ * DF) + t * DF;
        u32 w0 = (u32)f2h(xp[0]) | ((u32)f2h(xp[1]) << 16);
        u32 w1 = (u32)f2h(xp[2]) | ((u32)f2h(xp[3]) << 16);
        u32 w2 = (u32)f2h(xp[4]) | ((u32)f2h(xp[5]) << 16);
        *(uint4*)(smem + 32768 + t * 512 + r * 16) = make_uint4(w0, w1, w2, 0u);
    }
    // zero x pad rows 60..62 and h buffers [0]
    for (int i = tid; i < 384; i += 512) ((u32*)(smem + 32768 + 30720))[i] = 0u;
    for (int i = tid; i < 2048; i += 512) {
        ((u32*)smem)[i] = 0u;
        ((u32*)(smem + 16384))[i] = 0u;
    }

    uint4 wv[39];
#pragma unroll
    for (int s = 0; s < 39; ++s) wv[s] = pack[((j * 39 + s) << 6) + lane];

    const float br0 = bih0[hc] + bhh0[hc];
    const float bz0 = bih0[H + hc] + bhh0[H + hc];
    const float bgn0 = bhh0[2 * H + hc];
    const float bgi0 = bih0[2 * H + hc];
    const float br1 = bih1[hc] + bhh1[hc];
    const float bz1 = bih1[H + hc] + bhh1[H + hc];
    const float bgn1 = bhh1[2 * H + hc];
    const float bgi1 = bih1[2 * H + hc];

    float hs0[2][4] = {{0.f,0.f,0.f,0.f},{0.f,0.f,0.f,0.f}};
    float hs1[2][4] = {{0.f,0.f,0.f,0.f},{0.f,0.f,0.f,0.f}};

    __syncthreads();

    for (int t = 0; t < T_; ++t) {
        const int cur = (t & 1) << 13;   // 0 / 8192 byte offset
        const int nxt = cur ^ 8192;

        // ================= layer 0 =================
#pragma unroll
        for (int rt = 0; rt < 2; ++rt) {
            const int R = (rt << 4) + xr;
            uint4 a[5];
#pragma unroll
            for (int kt = 0; kt < 4; ++kt)
                a[kt] = *(const uint4*)(smem + cur + (R << 8) + ((((kt << 2) | g) ^ xr) << 4));
            a[4] = *(const uint4*)(smem + 32768 + ((t + g) << 9) + (R << 4));

            f32x4 aR = {0,0,0,0}, aZ = {0,0,0,0}, aG = {0,0,0,0}, aI = {0,0,0,0};
#pragma unroll
            for (int kt = 0; kt < 4; ++kt) {
                short8 av = __builtin_bit_cast(short8, a[kt]);
                aR = MFMA16(av, __builtin_bit_cast(short8, wv[kt]), aR, 0, 0, 0);
                aZ = MFMA16(av, __builtin_bit_cast(short8, wv[5 + kt]), aZ, 0, 0, 0);
                aG = MFMA16(av, __builtin_bit_cast(short8, wv[10 + kt]), aG, 0, 0, 0);
            }
            {
                short8 av = __builtin_bit_cast(short8, a[4]);
                aR = MFMA16(av, __builtin_bit_cast(short8, wv[4]), aR, 0, 0, 0);
                aZ = MFMA16(av, __builtin_bit_cast(short8, wv[9]), aZ, 0, 0, 0);
                aI = MFMA16(av, __builtin_bit_cast(short8, wv[14]), aI, 0, 0, 0);
            }
#pragma unroll
            for (int i = 0; i < 4; ++i) {
                float rg = 1.f / (1.f + __expf(-(aR[i] + br0)));
                float zg = 1.f / (1.f + __expf(-(aZ[i] + bz0)));
                float nn = aI[i] + bgi0 + rg * (aG[i] + bgn0);
                float e2 = __expf(2.f * nn);
                float ng = 1.f - 2.f / (e2 + 1.f);
                float hn = ng + zg * (hs0[rt][i] - ng);
                hs0[rt][i] = hn;
                int Rw = (rt << 4) + (g << 2) + i;
                *(unsigned short*)(smem + nxt + (Rw << 8) + (((hc >> 3) ^ (Rw & 15)) << 4) + ((hc & 7) << 1)) = f2h(hn);
            }
        }
        __syncthreads();

        // ================= layer 1 =================
#pragma unroll
        for (int rt = 0; rt < 2; ++rt) {
            const int R = (rt << 4) + xr;
            uint4 b[8];
#pragma unroll
            for (int kt = 0; kt < 4; ++kt)
                b[kt] = *(const uint4*)(smem + nxt + (R << 8) + ((((kt << 2) | g) ^ xr) << 4));
#pragma unroll
            for (int kt = 0; kt < 4; ++kt)
                b[4 + kt] = *(const uint4*)(smem + 16384 + cur + (R << 8) + ((((kt << 2) | g) ^ xr) << 4));

            f32x4 cR = {0,0,0,0}, cZ = {0,0,0,0}, cG = {0,0,0,0}, cI = {0,0,0,0};
#pragma unroll
            for (int kt = 0; kt < 8; ++kt) {
                short8 bv = __builtin_bit_cast(short8, b[kt]);
                cR = MFMA16(bv, __builtin_bit_cast(short8, wv[15 + kt]), cR, 0, 0, 0);
                cZ = MFMA16(bv, __builtin_bit_cast(short8, wv[23 + kt]), cZ, 0, 0, 0);
            }
#pragma unroll
            for (int kt = 0; kt < 4; ++kt) {
                short8 bv = __builtin_bit_cast(short8, b[4 + kt]);
                cG = MFMA16(bv, __builtin_bit_cast(short8, wv[31 + kt]), cG, 0, 0, 0);
            }
#pragma unroll
            for (int kt = 0; kt < 4; ++kt) {
                short8 bv = __builtin_bit_cast(short8, b[kt]);
                cI = MFMA16(bv, __builtin_bit_cast(short8, wv[35 + kt]), cI, 0, 0, 0);
            }
#pragma unroll
            for (int i = 0; i < 4; ++i) {
                float rg = 1.f / (1.f + __expf(-(cR[i] + br1)));
                float zg = 1.f / (1.f + __expf(-(cZ[i] + bz1)));
                float nn = cI[i] + bgi1 + rg * (cG[i] + bgn1);
                float e2 = __expf(2.f * nn);
                float ng = 1.f - 2.f / (e2 + 1.f);
                float hn = ng + zg * (hs1[rt][i] - ng);
                hs1[rt][i] = hn;
                int Rw = (rt << 4) + (g << 2) + i;
                *(unsigned short*)(smem + 16384 + nxt + (Rw << 8) + (((hc >> 3) ^ (Rw & 15)) << 4) + ((hc & 7) << 1)) = f2h(hn);
            }
        }
        __syncthreads();
    }

#pragma unroll
    for (int rt = 0; rt < 2; ++rt)
#pragma unroll
        for (int i = 0; i < 4; ++i) {
            int Rw = (rt << 4) + (g << 2) + i;
            hidden[(size_t)(n0 + Rw) * H + hc] = hs1[rt][i];
        }
}

// ------------------------------------------------------------------ epilogue (unchanged)
__global__ void k_rowstats(const float* __restrict__ hidden, const float* __restrict__ GH,
                           const float* __restrict__ wv1, const float* __restrict__ cc,
                           float* __restrict__ sx, float* __restrict__ invdv)
{
    int lane = threadIdx.x & 63;
    int wv = threadIdx.x >> 6;
    int n = blockIdx.x * 4 + wv;
    float p = hidden[(size_t)n * H + lane] * wv1[lane]
            + hidden[(size_t)n * H + 64 + lane] * wv1[64 + lane];
    float g = (lane < E_) ? GH[(size_t)n * E_ + lane] : 0.f;
#pragma unroll
    for (int off = 32; off > 0; off >>= 1) {
        p += __shfl_down(p, off);
        g += __shfl_down(g, off);
    }
    if (lane == 0) {
        sx[n] = p + cc[0];
        float dv = 0.5f * g;
        invdv[n] = (dv != 0.f) ? 1.f / dv : 0.f;
    }
}

__global__ void k_agg(const float* __restrict__ hidden, const float* __restrict__ GH,
                      float* __restrict__ agg, float* __restrict__ de)
{
    int t = threadIdx.x;
    int nbase = blockIdx.x * 128;
    if (t < H) {
        float part[E_];
#pragma unroll
        for (int e = 0; e < E_; ++e) part[e] = 0.f;
        for (int r = 0; r < 128; ++r) {
            int n = nbase + r;
            float hv = hidden[(size_t)n * H + t];
#pragma unroll
            for (int e = 0; e < E_; ++e) part[e] += GH[(size_t)n * E_ + e] * hv;
        }
#pragma unroll
        for (int e = 0; e < E_; ++e) atomicAdd(&agg[e * H + t], part[e]);
    } else if (t < H + E_) {
        int e = t - H;
        float s = 0.f;
        for (int r = 0; r < 128; ++r) s += GH[(size_t)(nbase + r) * E_ + e];
        atomicAdd(&de[e], s);
    }
}

__global__ void k_sy(const float* __restrict__ agg, const float* __restrict__ wv2,
                     const float* __restrict__ cc, const float* __restrict__ de,
                     float* __restrict__ sy, float* __restrict__ invde)
{
    int e = threadIdx.x;
    if (e < E_) {
        float s = 0.f;
        for (int h = 0; h < H; ++h) s += agg[e * H + h] * wv2[h];
        sy[e] = s + cc[1];
        float d = de[e];
        invde[e] = (d != 0.f) ? 1.f / d : 0.f;
    }
}

__global__ void k_attS(const float* __restrict__ hidden, const float* __restrict__ sx,
                       const float* __restrict__ sy, const float* __restrict__ invdv,
                       float* __restrict__ S)
{
    __shared__ float att_s[E_];
    __shared__ float sy_s[E_];
    int t = threadIdx.x;
    if (t < E_) sy_s[t] = sy[t];
    __syncthreads();
    float part[E_];
#pragma unroll
    for (int e = 0; e < E_; ++e) part[e] = 0.f;
    int nbase = blockIdx.x * 128;
    for (int r = 0; r < 128; ++r) {
        int n = nbase + r;
        if (t < 64) {
            float v = -1e30f;
            if (t < E_) {
                v = sx[n] + sy_s[t];
                v = (v >= 0.f) ? v : 0.01f * v;
            }
            float m = v;
#pragma unroll
            for (int off = 32; off > 0; off >>= 1) m = fmaxf(m, __shfl_down(m, off));
            m = __shfl(m, 0);
            float ev = (t < E_) ? __expf(v - m) : 0.f;
            float s = ev;
#pragma unroll
            for (int off = 32; off > 0; off >>= 1) s += __shfl_down(s, off);
            s = __shfl(s, 0);
            if (t < E_) att_s[t] = ev / s;
        }
        __syncthreads();
        if (t < H) {
            float hv = invdv[n] * hidden[(size_t)n * H + t];
#pragma unroll
            for (int e = 0; e < E_; ++e) part[e] += att_s[e] * hv;
        }
        __syncthreads();
    }
    if (t < H) {
#pragma unroll
        for (int e = 0; e < E_; ++e) atomicAdd(&S[e * H + t], part[e]);
    }
}

__global__ void k_final(const float* __restrict__ hidden, const float* __restrict__ sx,
                        const float* __restrict__ sy, const float* __restrict__ invdv,
                        const float* __restrict__ invde, const float* __restrict__ S,
                        const float* __restrict__ WfcT, const float* __restrict__ bfc,
                        const float* __restrict__ Wout, const float* __restrict__ bout,
                        float* __restrict__ out)
{
    __shared__ float S_s[E_ * H];
    __shared__ float sy_s[E_], ide_s[E_];
    __shared__ float newh[2][H];
    __shared__ float red[2][2];
    int t = threadIdx.x;
    for (int i = t; i < E_ * H; i += 256) S_s[i] = S[i];
    if (t < E_) { sy_s[t] = sy[t]; ide_s[t] = invde[t]; }
    __syncthreads();
    int slot = t >> 7, hcc = t & (H - 1);
    float wout_c = Wout[hcc];
    float bfc_c = bfc[hcc];
    float boutv = bout[0];
    for (int it = 0; it < 32; ++it) {
        int n = blockIdx.x * 64 + it * 2 + slot;
        float sxn = sx[n];
        float idv = invdv[n];
        float vv[E_];
        float m = -1e30f;
#pragma unroll
        for (int e = 0; e < E_; ++e) {
            float v = sxn + sy_s[e];
            v = (v >= 0.f) ? v : 0.01f * v;
            vv[e] = v;
            m = fmaxf(m, v);
        }
        float ssum = 0.f;
#pragma unroll
        for (int e = 0; e < E_; ++e) { vv[e] = __expf(vv[e] - m); ssum += vv[e]; }
        float sc = idv / ssum;
        float acc = hidden[(size_t)n * H + hcc];
#pragma unroll
        for (int e = 0; e < E_; ++e) acc += vv[e] * sc * ide_s[e] * S_s[e * H + hcc];
        newh[slot][hcc] = acc;
        __syncthreads();
        float f = bfc_c;
        for (int h = 0; h < H; ++h) f += newh[slot][h] * WfcT[h * H + hcc];
        f = (f >= 0.f) ? f : 0.01f * f;
        float op = f * wout_c;
#pragma unroll
        for (int off = 32; off > 0; off >>= 1) op += __shfl_down(op, off);
        if ((t & 63) == 0) red[slot][(t >> 6) & 1] = op;
        __syncthreads();
        if (hcc == 0) out[n] = red[slot][0] + red[slot][1] + boutv;
        __syncthreads();
    }
}

// ------------------------------------------------------------------ launcher
extern "C" void kernel_launch(void* const* d_in, const int* in_sizes, int n_in,
                              void* d_out, int out_size, void* d_ws, size_t ws_size,
                              hipStream_t stream)
{
    const float* x    = (const float*)d_in[0];
    const float* GH   = (const float*)d_in[1];
    const float* Wih0 = (const float*)d_in[2];
    const float* Whh0 = (const float*)d_in[3];
    const float* bih0 = (const float*)d_in[4];
    const float* bhh0 = (const float*)d_in[5];
    const float* Wih1 = (const float*)d_in[6];
    const float* Whh1 = (const float*)d_in[7];
    const float* bih1 = (const float*)d_in[8];
    const float* bhh1 = (const float*)d_in[9];
    const float* Wt   = (const float*)d_in[10];
    const float* bt   = (const float*)d_in[11];
    const float* a    = (const float*)d_in[12];
    const float* Wfc  = (const float*)d_in[13];
    const float* bfc  = (const float*)d_in[14];
    const float* Wout = (const float*)d_in[15];
    const float* bout = (const float*)d_in[16];

    float* ws    = (float*)d_ws;
    uint4* pack  = (uint4*)(ws + OFF_PACK);
    float* WfcT  = ws + OFF_WFCT;
    float* hid   = ws + OFF_HID;
    float* sx    = ws + OFF_SX;
    float* idv   = ws + OFF_IDV;
    float* agg   = ws + OFF_AGG;
    float* de    = ws + OFF_DE;
    float* S     = ws + OFF_S;
    float* ide   = ws + OFF_IDE;
    float* sy    = ws + OFF_SY;
    float* cc    = ws + OFF_CC;
    float* wv1   = ws + OFF_WV1;
    float* wv2   = ws + OFF_WV2;

    k_pack<<<78, 256, 0, stream>>>(Wih0, Whh0, Wih1, Whh1, pack);
    k_prep_fc<<<64, 256, 0, stream>>>(Wfc, WfcT);
    k_prep_wv<<<1, 128, 0, stream>>>(Wt, bt, a, wv1, wv2, cc);
    k_zero<<<31, 256, 0, stream>>>(agg);

    const size_t lds_bytes = 65024;
    (void)hipFuncSetAttribute((const void*)k_gru,
                              hipFuncAttributeMaxDynamicSharedMemorySize,
                              (int)lds_bytes);
    k_gru<<<256, 512, lds_bytes, stream>>>(x, pack, bih0, bhh0, bih1, bhh1, hid);

    k_rowstats<<<2048, 256, 0, stream>>>(hid, GH, wv1, cc, sx, idv);
    k_agg<<<64, 256, 0, stream>>>(hid, GH, agg, de);
    k_sy<<<1, 64, 0, stream>>>(agg, wv2, cc, de, sy, ide);
    k_attS<<<64, 256, 0, stream>>>(hid, sx, sy, idv, S);
    k_final<<<128, 256, 0, stream>>>(hid, sx, sy, idv, ide, S, WfcT, bfc,
                                     Wout, bout, (float*)d_out);
}

// Round 4
// 353.495 us; speedup vs baseline: 18.4217x; 1.4716x over previous
//
#include <hip/hip_runtime.h>
#include <hip/hip_fp16.h>
#include <cstddef>

#define H 128
#define E_ 30
#define T_ 60
#define DF 6

typedef unsigned int u32;
typedef __attribute__((ext_vector_type(8))) short short8;
typedef __attribute__((ext_vector_type(4))) float f32x4;

// ---- workspace layout (float offsets) ----
#define OFF_PACK   0          // uint4[8*39*64] fp16 weights
#define OFF_WFCT   79872      // Wfc^T [128][128]
#define OFF_HID    96256      // hidden [8192][128]
#define OFF_SX     1144832
#define OFF_IDV    1153024
#define OFF_AGG    1161216
#define OFF_DE     1165056
#define OFF_S      1165088
#define OFF_IDE    1168928
#define OFF_SY     1168960
#define OFF_CC     1168992
#define OFF_WV1    1169024
#define OFF_WV2    1169152
#define ZERO_CNT   7712       // agg+de+S contiguous

__device__ __forceinline__ unsigned short f2h(float f) {
    return __half_as_ushort(__float2half(f));
}

// ------------------------------------------------------------------ weight packing (fp16)
// B-fragment order for mfma_f32_16x16x32_f16: lane l holds B[k][c] with
// c = hc0 + (l&15), k = kt*32 + 8*(l>>4) + i  (8 consecutive k per lane).
// Slots per hc-group j (39 total):
//  L0: s0-4 r (K=160: h0|x|pad), s5-9 z, s10-13 ghn (K=128), s14 gin (x, Kpad32)
//  L1: s15-22 r (K=256: y|h1), s23-30 z, s31-34 ghn (h1), s35-38 gin (y)
__global__ void k_pack(const float* __restrict__ Wih0, const float* __restrict__ Whh0,
                       const float* __restrict__ Wih1, const float* __restrict__ Whh1,
                       uint4* __restrict__ pack)
{
    int u = blockIdx.x * 256 + threadIdx.x;   // 78*256 = 19968 exact
    int lane = u & 63;
    int s = (u >> 6) % 39;
    int j = (u >> 6) / 39;
    int hc = j * 16 + (lane & 15);
    int g = lane >> 4;
    int layer, gate, kt;
    if (s < 5)       { layer = 0; gate = 0; kt = s; }
    else if (s < 10) { layer = 0; gate = 1; kt = s - 5; }
    else if (s < 14) { layer = 0; gate = 2; kt = s - 10; }
    else if (s < 15) { layer = 0; gate = 3; kt = 0; }
    else if (s < 23) { layer = 1; gate = 0; kt = s - 15; }
    else if (s < 31) { layer = 1; gate = 1; kt = s - 23; }
    else if (s < 35) { layer = 1; gate = 2; kt = s - 31; }
    else             { layer = 1; gate = 3; kt = s - 35; }

    u32 wd[4];
    for (int p = 0; p < 4; ++p) {
        unsigned short hh[2];
        for (int q = 0; q < 2; ++q) {
            int k = kt * 32 + g * 8 + p * 2 + q;
            float v = 0.f;
            if (layer == 0) {
                if (gate <= 1) {
                    int row = gate * 128 + hc;
                    if (k < 128) v = Whh0[row * 128 + k];
                    else if (k < 134) v = Wih0[row * 6 + (k - 128)];
                } else if (gate == 2) {
                    v = Whh0[(256 + hc) * 128 + k];
                } else {
                    if (k < 6) v = Wih0[(256 + hc) * 6 + k];
                }
            } else {
                if (gate <= 1) {
                    int row = gate * 128 + hc;
                    v = (k < 128) ? Wih1[row * 128 + k] : Whh1[row * 128 + (k - 128)];
                } else if (gate == 2) {
                    v = Whh1[(256 + hc) * 128 + k];
                } else {
                    v = Wih1[(256 + hc) * 128 + k];
                }
            }
            hh[q] = f2h(v);
        }
        wd[p] = (u32)hh[0] | ((u32)hh[1] << 16);
    }
    pack[(j * 39 + s) * 64 + lane] = make_uint4(wd[0], wd[1], wd[2], wd[3]);
}

__global__ void k_prep_fc(const float* __restrict__ Wfc, float* __restrict__ WfcT)
{
    int i = blockIdx.x * 256 + threadIdx.x;   // 64*256 = 16384
    int col = i / 128, h = i % 128;
    WfcT[h * 128 + col] = Wfc[i];
}

__global__ void k_prep_wv(const float* __restrict__ Wt, const float* __restrict__ bt,
                          const float* __restrict__ a, float* __restrict__ wv1,
                          float* __restrict__ wv2, float* __restrict__ cc)
{
    int i = threadIdx.x;  // 0..127
    float s1 = 0.f, s2 = 0.f;
    for (int j = 0; j < H; ++j) {
        float w = Wt[(size_t)j * H + i];
        s1 += w * a[j];
        s2 += w * a[H + j];
    }
    wv1[i] = s1;
    wv2[i] = s2;
    if (i == 0) {
        float c1 = 0.f, c2 = 0.f;
        for (int j = 0; j < H; ++j) { c1 += bt[j] * a[j]; c2 += bt[j] * a[H + j]; }
        cc[0] = c1; cc[1] = c2;
    }
}

__global__ void k_zero(float* __restrict__ z)
{
    int i = blockIdx.x * 256 + threadIdx.x;
    if (i < ZERO_CNT) z[i] = 0.f;
}

// ------------------------------------------------------------------ fused 2-layer GRU (MFMA fp16)
// Skewed pipeline: phase t computes L0(t) AND L1(t-1) with ONE barrier.
// L1(t-1)'s y-operand = h0(t-1) = the same A-fragments L0(t) reads.
// h0(s) -> h0buf[s&1]; h1(s) -> h1buf[s&1].
#define MFMA16 __builtin_amdgcn_mfma_f32_16x16x32_f16

__global__ __launch_bounds__(512, 2) void k_gru(
    const float* __restrict__ x,
    const uint4* __restrict__ pack,
    const float* __restrict__ bih0, const float* __restrict__ bhh0,
    const float* __restrict__ bih1, const float* __restrict__ bhh1,
    float* __restrict__ hidden)
{
    extern __shared__ char smem[];
    // [0,16384): h0[2][32][128]f16  [16384,32768): h1[2]  [32768,65024): x[63][32]x16B
    const int tid = threadIdx.x;
    const int lane = tid & 63;
    const int j = tid >> 6;             // wave index = hidden col group
    const int xr = lane & 15;
    const int g = lane >> 4;
    const int hc = (j << 4) + xr;       // D-fragment col (hidden unit)
    const int n0 = blockIdx.x << 5;

    // x preload: cell (r,t) = 6 fp16 + 2 zero pads, at 32768 + t*512 + r*16
    for (int c = tid; c < 32 * 60; c += 512) {
        int r = c / 60, t = c % 60;
        const float* xp = x + (size_t)(n0 + r) * (T_ * DF) + t * DF;
        u32 w0 = (u32)f2h(xp[0]) | ((u32)f2h(xp[1]) << 16);
        u32 w1 = (u32)f2h(xp[2]) | ((u32)f2h(xp[3]) << 16);
        u32 w2 = (u32)f2h(xp[4]) | ((u32)f2h(xp[5]) << 16);
        *(uint4*)(smem + 32768 + t * 512 + r * 16) = make_uint4(w0, w1, w2, 0u);
    }
    // zero x pad rows 60..62 and both parities of h buffers
    for (int i = tid; i < 384; i += 512) ((u32*)(smem + 32768 + 30720))[i] = 0u;
    for (int i = tid; i < 4096; i += 512) {
        ((u32*)smem)[i] = 0u;
        ((u32*)(smem + 16384))[i] = 0u;
    }

    uint4 wv[39];
#pragma unroll
    for (int s = 0; s < 39; ++s) wv[s] = pack[((j * 39 + s) << 6) + lane];

    const float br0 = bih0[hc] + bhh0[hc];
    const float bz0 = bih0[H + hc] + bhh0[H + hc];
    const float bgn0 = bhh0[2 * H + hc];
    const float bgi0 = bih0[2 * H + hc];
    const float br1 = bih1[hc] + bhh1[hc];
    const float bz1 = bih1[H + hc] + bhh1[H + hc];
    const float bgn1 = bhh1[2 * H + hc];
    const float bgi1 = bih1[2 * H + hc];

    float hs0[2][4] = {{0.f,0.f,0.f,0.f},{0.f,0.f,0.f,0.f}};
    float hs1[2][4] = {{0.f,0.f,0.f,0.f},{0.f,0.f,0.f,0.f}};

    __syncthreads();

    for (int t = 0; t <= T_; ++t) {
        const int pr  = (t & 1) << 13;   // h0 write / h1 read parity (byte)
        const int prx = pr ^ 8192;       // h0 read / h1 write parity

#pragma unroll
        for (int rt = 0; rt < 2; ++rt) {
            const int R = (rt << 4) + xr;
            const int rowb = R << 8;

            // f0 = h0(t-1) fragments — shared by L0(t) and L1(t-1)
            uint4 f0[4];
#pragma unroll
            for (int kt = 0; kt < 4; ++kt)
                f0[kt] = *(const uint4*)(smem + prx + rowb + ((((kt << 2) | g) ^ xr) << 4));

            f32x4 aR = {0,0,0,0}, aZ = {0,0,0,0}, aG = {0,0,0,0}, aI = {0,0,0,0};
            f32x4 cR = {0,0,0,0}, cZ = {0,0,0,0}, cG = {0,0,0,0}, cI = {0,0,0,0};

            if (t < T_) {
                uint4 fx = *(const uint4*)(smem + 32768 + ((t + g) << 9) + (R << 4));
                short8 xv = __builtin_bit_cast(short8, fx);
#pragma unroll
                for (int kt = 0; kt < 4; ++kt) {
                    short8 av = __builtin_bit_cast(short8, f0[kt]);
                    aR = MFMA16(av, __builtin_bit_cast(short8, wv[kt]), aR, 0, 0, 0);
                    aZ = MFMA16(av, __builtin_bit_cast(short8, wv[5 + kt]), aZ, 0, 0, 0);
                    aG = MFMA16(av, __builtin_bit_cast(short8, wv[10 + kt]), aG, 0, 0, 0);
                }
                aR = MFMA16(xv, __builtin_bit_cast(short8, wv[4]), aR, 0, 0, 0);
                aZ = MFMA16(xv, __builtin_bit_cast(short8, wv[9]), aZ, 0, 0, 0);
                aI = MFMA16(xv, __builtin_bit_cast(short8, wv[14]), aI, 0, 0, 0);
            }

            if (t > 0) {
                // y-part of L1(t-1): reuse f0
#pragma unroll
                for (int kt = 0; kt < 4; ++kt) {
                    short8 av = __builtin_bit_cast(short8, f0[kt]);
                    cR = MFMA16(av, __builtin_bit_cast(short8, wv[15 + kt]), cR, 0, 0, 0);
                    cZ = MFMA16(av, __builtin_bit_cast(short8, wv[23 + kt]), cZ, 0, 0, 0);
                    cI = MFMA16(av, __builtin_bit_cast(short8, wv[35 + kt]), cI, 0, 0, 0);
                }
                // h1-part: f1 = h1(t-2)
#pragma unroll
                for (int kt = 0; kt < 4; ++kt) {
                    uint4 f1 = *(const uint4*)(smem + 16384 + pr + rowb + ((((kt << 2) | g) ^ xr) << 4));
                    short8 bv = __builtin_bit_cast(short8, f1);
                    cR = MFMA16(bv, __builtin_bit_cast(short8, wv[19 + kt]), cR, 0, 0, 0);
                    cZ = MFMA16(bv, __builtin_bit_cast(short8, wv[27 + kt]), cZ, 0, 0, 0);
                    cG = MFMA16(bv, __builtin_bit_cast(short8, wv[31 + kt]), cG, 0, 0, 0);
                }
            }

            if (t < T_) {
#pragma unroll
                for (int i = 0; i < 4; ++i) {
                    float rg = 1.f / (1.f + __expf(-(aR[i] + br0)));
                    float zg = 1.f / (1.f + __expf(-(aZ[i] + bz0)));
                    float nn = aI[i] + bgi0 + rg * (aG[i] + bgn0);
                    float e2 = __expf(2.f * nn);
                    float ng = 1.f - 2.f / (e2 + 1.f);
                    float hn = ng + zg * (hs0[rt][i] - ng);
                    hs0[rt][i] = hn;
                    int Rw = (rt << 4) + (g << 2) + i;
                    *(unsigned short*)(smem + pr + (Rw << 8) + (((hc >> 3) ^ (Rw & 15)) << 4) + ((hc & 7) << 1)) = f2h(hn);
                }
            }
            if (t > 0) {
#pragma unroll
                for (int i = 0; i < 4; ++i) {
                    float rg = 1.f / (1.f + __expf(-(cR[i] + br1)));
                    float zg = 1.f / (1.f + __expf(-(cZ[i] + bz1)));
                    float nn = cI[i] + bgi1 + rg * (cG[i] + bgn1);
                    float e2 = __expf(2.f * nn);
                    float ng = 1.f - 2.f / (e2 + 1.f);
                    float hn = ng + zg * (hs1[rt][i] - ng);
                    hs1[rt][i] = hn;
                    int Rw = (rt << 4) + (g << 2) + i;
                    *(unsigned short*)(smem + 16384 + prx + (Rw << 8) + (((hc >> 3) ^ (Rw & 15)) << 4) + ((hc & 7) << 1)) = f2h(hn);
                }
            }
        }
        __syncthreads();
    }

#pragma unroll
    for (int rt = 0; rt < 2; ++rt)
#pragma unroll
        for (int i = 0; i < 4; ++i) {
            int Rw = (rt << 4) + (g << 2) + i;
            hidden[(size_t)(n0 + Rw) * H + hc] = hs1[rt][i];
        }
}

// ------------------------------------------------------------------ epilogue
__global__ void k_rowstats(const float* __restrict__ hidden, const float* __restrict__ GH,
                           const float* __restrict__ wv1, const float* __restrict__ cc,
                           float* __restrict__ sx, float* __restrict__ invdv)
{
    int lane = threadIdx.x & 63;
    int wv = threadIdx.x >> 6;
    int n = blockIdx.x * 4 + wv;
    float p = hidden[(size_t)n * H + lane] * wv1[lane]
            + hidden[(size_t)n * H + 64 + lane] * wv1[64 + lane];
    float g = (lane < E_) ? GH[(size_t)n * E_ + lane] : 0.f;
#pragma unroll
    for (int off = 32; off > 0; off >>= 1) {
        p += __shfl_down(p, off);
        g += __shfl_down(g, off);
    }
    if (lane == 0) {
        sx[n] = p + cc[0];
        float dv = 0.5f * g;
        invdv[n] = (dv != 0.f) ? 1.f / dv : 0.f;
    }
}

// 256 blocks x 32 rows
__global__ void k_agg(const float* __restrict__ hidden, const float* __restrict__ GH,
                      float* __restrict__ agg, float* __restrict__ de)
{
    int t = threadIdx.x;
    int nbase = blockIdx.x * 32;
    if (t < H) {
        float part[E_];
#pragma unroll
        for (int e = 0; e < E_; ++e) part[e] = 0.f;
        for (int r = 0; r < 32; ++r) {
            int n = nbase + r;
            float hv = hidden[(size_t)n * H + t];
#pragma unroll
            for (int e = 0; e < E_; ++e) part[e] += GH[(size_t)n * E_ + e] * hv;
        }
#pragma unroll
        for (int e = 0; e < E_; ++e) atomicAdd(&agg[e * H + t], part[e]);
    } else if (t < H + E_) {
        int e = t - H;
        float s = 0.f;
        for (int r = 0; r < 32; ++r) s += GH[(size_t)(nbase + r) * E_ + e];
        atomicAdd(&de[e], s);
    }
}

__global__ void k_sy(const float* __restrict__ agg, const float* __restrict__ wv2,
                     const float* __restrict__ cc, const float* __restrict__ de,
                     float* __restrict__ sy, float* __restrict__ invde)
{
    int e = threadIdx.x;
    if (e < E_) {
        float s = 0.f;
        for (int h = 0; h < H; ++h) s += agg[e * H + h] * wv2[h];
        sy[e] = s + cc[1];
        float d = de[e];
        invde[e] = (d != 0.f) ? 1.f / d : 0.f;
    }
}

// 256 blocks x 32 rows, one barrier; invdv folded into att
__global__ void k_attS(const float* __restrict__ hidden, const float* __restrict__ sx,
                       const float* __restrict__ sy, const float* __restrict__ invdv,
                       float* __restrict__ S)
{
    __shared__ float att_s[32][E_];
    __shared__ float sy_s[E_];
    int t = threadIdx.x;
    if (t < E_) sy_s[t] = sy[t];
    __syncthreads();
    int nbase = blockIdx.x * 32;
    if (t < 32) {
        int n = nbase + t;
        float sxn = sx[n];
        float vv[E_];
        float m = -1e30f;
#pragma unroll
        for (int e = 0; e < E_; ++e) {
            float v = sxn + sy_s[e];
            v = (v >= 0.f) ? v : 0.01f * v;
            vv[e] = v;
            m = fmaxf(m, v);
        }
        float ss = 0.f;
#pragma unroll
        for (int e = 0; e < E_; ++e) { vv[e] = __expf(vv[e] - m); ss += vv[e]; }
        float sc = invdv[n] / ss;
#pragma unroll
        for (int e = 0; e < E_; ++e) att_s[t][e] = vv[e] * sc;
    }
    __syncthreads();
    if (t < H) {
        float part[E_];
#pragma unroll
        for (int e = 0; e < E_; ++e) part[e] = 0.f;
        for (int r = 0; r < 32; ++r) {
            float hv = hidden[(size_t)(nbase + r) * H + t];
#pragma unroll
            for (int e = 0; e < E_; ++e) part[e] += att_s[r][e] * hv;
        }
#pragma unroll
        for (int e = 0; e < E_; ++e) atomicAdd(&S[e * H + t], part[e]);
    }
}

// 256 blocks x 256 threads; wave-per-row, 8 rows per wave
__global__ __launch_bounds__(256) void k_final(
    const float* __restrict__ hidden, const float* __restrict__ sx,
    const float* __restrict__ sy, const float* __restrict__ invdv,
    const float* __restrict__ invde, const float* __restrict__ S,
    const float* __restrict__ WfcT, const float* __restrict__ bfc,
    const float* __restrict__ Wout, const float* __restrict__ bout,
    float* __restrict__ out)
{
    __shared__ float S_s[E_ * H];
    __shared__ float sy_s[E_], ide_s[E_];
    __shared__ float nh[4][H];
    int t = threadIdx.x;
    for (int i = t; i < E_ * H; i += 256) S_s[i] = S[i];
    if (t < E_) { sy_s[t] = sy[t]; ide_s[t] = invde[t]; }
    __syncthreads();
    int wv = t >> 6, lane = t & 63;
    float wouta = Wout[lane], woutb = Wout[64 + lane];
    float bfca = bfc[lane], bfcb = bfc[64 + lane];
    float boutv = bout[0];
    for (int it = 0; it < 8; ++it) {
        int n = blockIdx.x * 32 + it * 4 + wv;
        float sxn = sx[n];
        float idv = invdv[n];
        float vv[E_];
        float m = -1e30f;
#pragma unroll
        for (int e = 0; e < E_; ++e) {
            float v = sxn + sy_s[e];
            v = (v >= 0.f) ? v : 0.01f * v;
            vv[e] = v;
            m = fmaxf(m, v);
        }
        float ss = 0.f;
#pragma unroll
        for (int e = 0; e < E_; ++e) { vv[e] = __expf(vv[e] - m); ss += vv[e]; }
        float sc = idv / ss;
        float a0 = hidden[(size_t)n * H + lane];
        float a1 = hidden[(size_t)n * H + 64 + lane];
#pragma unroll
        for (int e = 0; e < E_; ++e) {
            float wgt = vv[e] * sc * ide_s[e];
            a0 += wgt * S_s[e * H + lane];
            a1 += wgt * S_s[e * H + 64 + lane];
        }
        nh[wv][lane] = a0;
        nh[wv][64 + lane] = a1;
        __syncthreads();
        float f0 = bfca, f1 = bfcb;
        for (int h = 0; h < H; h += 4) {
            float4 nv = *(const float4*)&nh[wv][h];
            f0 += nv.x * WfcT[(h + 0) * H + lane] + nv.y * WfcT[(h + 1) * H + lane]
                + nv.z * WfcT[(h + 2) * H + lane] + nv.w * WfcT[(h + 3) * H + lane];
            f1 += nv.x * WfcT[(h + 0) * H + 64 + lane] + nv.y * WfcT[(h + 1) * H + 64 + lane]
                + nv.z * WfcT[(h + 2) * H + 64 + lane] + nv.w * WfcT[(h + 3) * H + 64 + lane];
        }
        f0 = (f0 >= 0.f) ? f0 : 0.01f * f0;
        f1 = (f1 >= 0.f) ? f1 : 0.01f * f1;
        float op = f0 * wouta + f1 * woutb;
#pragma unroll
        for (int off = 32; off > 0; off >>= 1) op += __shfl_down(op, off);
        if (lane == 0) out[n] = op + boutv;
        __syncthreads();
    }
}

// ------------------------------------------------------------------ launcher
extern "C" void kernel_launch(void* const* d_in, const int* in_sizes, int n_in,
                              void* d_out, int out_size, void* d_ws, size_t ws_size,
                              hipStream_t stream)
{
    const float* x    = (const float*)d_in[0];
    const float* GH   = (const float*)d_in[1];
    const float* Wih0 = (const float*)d_in[2];
    const float* Whh0 = (const float*)d_in[3];
    const float* bih0 = (const float*)d_in[4];
    const float* bhh0 = (const float*)d_in[5];
    const float* Wih1 = (const float*)d_in[6];
    const float* Whh1 = (const float*)d_in[7];
    const float* bih1 = (const float*)d_in[8];
    const float* bhh1 = (const float*)d_in[9];
    const float* Wt   = (const float*)d_in[10];
    const float* bt   = (const float*)d_in[11];
    const float* a    = (const float*)d_in[12];
    const float* Wfc  = (const float*)d_in[13];
    const float* bfc  = (const float*)d_in[14];
    const float* Wout = (const float*)d_in[15];
    const float* bout = (const float*)d_in[16];

    float* ws    = (float*)d_ws;
    uint4* pack  = (uint4*)(ws + OFF_PACK);
    float* WfcT  = ws + OFF_WFCT;
    float* hid   = ws + OFF_HID;
    float* sx    = ws + OFF_SX;
    float* idv   = ws + OFF_IDV;
    float* agg   = ws + OFF_AGG;
    float* de    = ws + OFF_DE;
    float* S     = ws + OFF_S;
    float* ide   = ws + OFF_IDE;
    float* sy    = ws + OFF_SY;
    float* cc    = ws + OFF_CC;
    float* wv1   = ws + OFF_WV1;
    float* wv2   = ws + OFF_WV2;

    k_pack<<<78, 256, 0, stream>>>(Wih0, Whh0, Wih1, Whh1, pack);
    k_prep_fc<<<64, 256, 0, stream>>>(Wfc, WfcT);
    k_prep_wv<<<1, 128, 0, stream>>>(Wt, bt, a, wv1, wv2, cc);
    k_zero<<<31, 256, 0, stream>>>(agg);

    const size_t lds_bytes = 65024;
    (void)hipFuncSetAttribute((const void*)k_gru,
                              hipFuncAttributeMaxDynamicSharedMemorySize,
                              (int)lds_bytes);
    k_gru<<<256, 512, lds_bytes, stream>>>(x, pack, bih0, bhh0, bih1, bhh1, hid);

    k_rowstats<<<2048, 256, 0, stream>>>(hid, GH, wv1, cc, sx, idv);
    k_agg<<<256, 256, 0, stream>>>(hid, GH, agg, de);
    k_sy<<<1, 64, 0, stream>>>(agg, wv2, cc, de, sy, ide);
    k_attS<<<256, 256, 0, stream>>>(hid, sx, sy, idv, S);
    k_final<<<256, 256, 0, stream>>>(hid, sx, sy, idv, ide, S, WfcT, bfc,
                                     Wout, bout, (float*)d_out);
}

// Round 5
// 333.733 us; speedup vs baseline: 19.5126x; 1.0592x over previous
//
#include <hip/hip_runtime.h>
#include <hip/hip_fp16.h>
#include <cstddef>

#define H 128
#define E_ 30
#define T_ 60
#define DF 6

typedef unsigned int u32;
typedef __attribute__((ext_vector_type(8))) short short8;
typedef __attribute__((ext_vector_type(4))) float f32x4;

// ---- workspace layout (float offsets) ----
#define OFF_PACK   0          // uint4[8*39*64] fp16 weights
#define OFF_WFCT   79872      // Wfc^T [128][128]
#define OFF_HID    96256      // hidden [8192][128]
#define OFF_SX     1144832
#define OFF_IDV    1153024
#define OFF_AGG    1161216
#define OFF_DE     1165056
#define OFF_S      1165088
#define OFF_IDE    1168928
#define OFF_SY     1168960
#define OFF_CC     1168992
#define OFF_WV1    1169024
#define OFF_WV2    1169152
#define ZERO_CNT   7712       // agg+de+S contiguous

__device__ __forceinline__ unsigned short f2h(float f) {
    return __half_as_ushort(__float2half(f));
}

// ------------------------------------------------------------------ weight packing (fp16)
// B-fragment order for mfma_f32_16x16x32_f16: lane l holds B[k][c] with
// c = hc0 + (l&15), k = kt*32 + 8*(l>>4) + i  (8 consecutive k per lane).
// Slots per hc-group j (39 total):
//  L0: s0-4 r (K=160: h0|x|pad), s5-9 z, s10-13 ghn (K=128), s14 gin (x, Kpad32)
//  L1: s15-22 r (K=256: y|h1), s23-30 z, s31-34 ghn (h1), s35-38 gin (y)
__global__ void k_pack(const float* __restrict__ Wih0, const float* __restrict__ Whh0,
                       const float* __restrict__ Wih1, const float* __restrict__ Whh1,
                       uint4* __restrict__ pack)
{
    int u = blockIdx.x * 256 + threadIdx.x;   // 78*256 = 19968 exact
    int lane = u & 63;
    int s = (u >> 6) % 39;
    int j = (u >> 6) / 39;
    int hc = j * 16 + (lane & 15);
    int g = lane >> 4;
    int layer, gate, kt;
    if (s < 5)       { layer = 0; gate = 0; kt = s; }
    else if (s < 10) { layer = 0; gate = 1; kt = s - 5; }
    else if (s < 14) { layer = 0; gate = 2; kt = s - 10; }
    else if (s < 15) { layer = 0; gate = 3; kt = 0; }
    else if (s < 23) { layer = 1; gate = 0; kt = s - 15; }
    else if (s < 31) { layer = 1; gate = 1; kt = s - 23; }
    else if (s < 35) { layer = 1; gate = 2; kt = s - 31; }
    else             { layer = 1; gate = 3; kt = s - 35; }

    u32 wd[4];
    for (int p = 0; p < 4; ++p) {
        unsigned short hh[2];
        for (int q = 0; q < 2; ++q) {
            int k = kt * 32 + g * 8 + p * 2 + q;
            float v = 0.f;
            if (layer == 0) {
                if (gate <= 1) {
                    int row = gate * 128 + hc;
                    if (k < 128) v = Whh0[row * 128 + k];
                    else if (k < 134) v = Wih0[row * 6 + (k - 128)];
                } else if (gate == 2) {
                    v = Whh0[(256 + hc) * 128 + k];
                } else {
                    if (k < 6) v = Wih0[(256 + hc) * 6 + k];
                }
            } else {
                if (gate <= 1) {
                    int row = gate * 128 + hc;
                    v = (k < 128) ? Wih1[row * 128 + k] : Whh1[row * 128 + (k - 128)];
                } else if (gate == 2) {
                    v = Whh1[(256 + hc) * 128 + k];
                } else {
                    v = Wih1[(256 + hc) * 128 + k];
                }
            }
            hh[q] = f2h(v);
        }
        wd[p] = (u32)hh[0] | ((u32)hh[1] << 16);
    }
    pack[(j * 39 + s) * 64 + lane] = make_uint4(wd[0], wd[1], wd[2], wd[3]);
}

__global__ void k_prep_fc(const float* __restrict__ Wfc, float* __restrict__ WfcT)
{
    int i = blockIdx.x * 256 + threadIdx.x;   // 64*256 = 16384
    int col = i / 128, h = i % 128;
    WfcT[h * 128 + col] = Wfc[i];
}

__global__ void k_prep_wv(const float* __restrict__ Wt, const float* __restrict__ bt,
                          const float* __restrict__ a, float* __restrict__ wv1,
                          float* __restrict__ wv2, float* __restrict__ cc)
{
    int i = threadIdx.x;  // 0..127
    float s1 = 0.f, s2 = 0.f;
    for (int j = 0; j < H; ++j) {
        float w = Wt[(size_t)j * H + i];
        s1 += w * a[j];
        s2 += w * a[H + j];
    }
    wv1[i] = s1;
    wv2[i] = s2;
    if (i == 0) {
        float c1 = 0.f, c2 = 0.f;
        for (int j = 0; j < H; ++j) { c1 += bt[j] * a[j]; c2 += bt[j] * a[H + j]; }
        cc[0] = c1; cc[1] = c2;
    }
}

__global__ void k_zero(float* __restrict__ z)
{
    int i = blockIdx.x * 256 + threadIdx.x;
    if (i < ZERO_CNT) z[i] = 0.f;
}

// ------------------------------------------------------------------ fused 2-layer GRU (MFMA fp16)
// Skewed pipeline (one barrier/step) + unroll-by-2 (compile-time parity ->
// LDS addrs loop-invariant, parity as ds offset immediates) + v_rcp_f32
// activations (no precise-divide sequences; no -ffast-math in harness).
#define MFMA16 __builtin_amdgcn_mfma_f32_16x16x32_f16

#define RD_H0(rt, kt, PRX) (*(const uint4*)(smem + (PRX) + ((((rt)<<4)+xr) << 8) + ((((((kt)<<2) | g)) ^ xr) << 4)))
#define RD_H1(rt, kt, PRR) (*(const uint4*)(smem + 16384 + (PRR) + ((((rt)<<4)+xr) << 8) + ((((((kt)<<2) | g)) ^ xr) << 4)))

#define GRU_STEP(PR, DO_L0, DO_L1, XPA, XPB) do { \
  _Pragma("unroll") \
  for (int rt = 0; rt < 2; ++rt) { \
    uint4 f0[4]; \
    _Pragma("unroll") \
    for (int kt = 0; kt < 4; ++kt) f0[kt] = RD_H0(rt, kt, (PR)^8192); \
    f32x4 aR={0,0,0,0}, aZ={0,0,0,0}, aG={0,0,0,0}, aI={0,0,0,0}; \
    f32x4 cR={0,0,0,0}, cZ={0,0,0,0}, cG={0,0,0,0}, cI={0,0,0,0}; \
    if (DO_L0) { \
      uint4 fx = *(const uint4*)((rt == 0) ? (XPA) : (XPB)); \
      short8 xv = __builtin_bit_cast(short8, fx); \
      _Pragma("unroll") \
      for (int kt = 0; kt < 4; ++kt) { \
        short8 av = __builtin_bit_cast(short8, f0[kt]); \
        aR = MFMA16(av, __builtin_bit_cast(short8, wv[kt]), aR, 0, 0, 0); \
        aZ = MFMA16(av, __builtin_bit_cast(short8, wv[5+kt]), aZ, 0, 0, 0); \
        aG = MFMA16(av, __builtin_bit_cast(short8, wv[10+kt]), aG, 0, 0, 0); \
      } \
      aR = MFMA16(xv, __builtin_bit_cast(short8, wv[4]), aR, 0, 0, 0); \
      aZ = MFMA16(xv, __builtin_bit_cast(short8, wv[9]), aZ, 0, 0, 0); \
      aI = MFMA16(xv, __builtin_bit_cast(short8, wv[14]), aI, 0, 0, 0); \
    } \
    if (DO_L1) { \
      _Pragma("unroll") \
      for (int kt = 0; kt < 4; ++kt) { \
        short8 av = __builtin_bit_cast(short8, f0[kt]); \
        cR = MFMA16(av, __builtin_bit_cast(short8, wv[15+kt]), cR, 0, 0, 0); \
        cZ = MFMA16(av, __builtin_bit_cast(short8, wv[23+kt]), cZ, 0, 0, 0); \
        cI = MFMA16(av, __builtin_bit_cast(short8, wv[35+kt]), cI, 0, 0, 0); \
      } \
      _Pragma("unroll") \
      for (int kt = 0; kt < 4; ++kt) { \
        uint4 f1 = RD_H1(rt, kt, (PR)); \
        short8 bv = __builtin_bit_cast(short8, f1); \
        cR = MFMA16(bv, __builtin_bit_cast(short8, wv[19+kt]), cR, 0, 0, 0); \
        cZ = MFMA16(bv, __builtin_bit_cast(short8, wv[27+kt]), cZ, 0, 0, 0); \
        cG = MFMA16(bv, __builtin_bit_cast(short8, wv[31+kt]), cG, 0, 0, 0); \
      } \
    } \
    if (DO_L0) { \
      _Pragma("unroll") \
      for (int i = 0; i < 4; ++i) { \
        float er = __expf(-(aR[i] + br0)); \
        float rg = __builtin_amdgcn_rcpf(1.f + er); \
        float ez = __expf(-(aZ[i] + bz0)); \
        float zg = __builtin_amdgcn_rcpf(1.f + ez); \
        float nn = aI[i] + bgi0 + rg * (aG[i] + bgn0); \
        float e2 = __expf(2.f * nn); \
        float ng = 1.f - 2.f * __builtin_amdgcn_rcpf(e2 + 1.f); \
        float hn = ng + zg * (hs0[rt][i] - ng); \
        hs0[rt][i] = hn; \
        const int Rw = (rt << 4) + (g << 2) + i; \
        *(unsigned short*)(smem + (PR) + (Rw << 8) + (((hc >> 3) ^ (Rw & 15)) << 4) + ((hc & 7) << 1)) = f2h(hn); \
      } \
    } \
    if (DO_L1) { \
      _Pragma("unroll") \
      for (int i = 0; i < 4; ++i) { \
        float er = __expf(-(cR[i] + br1)); \
        float rg = __builtin_amdgcn_rcpf(1.f + er); \
        float ez = __expf(-(cZ[i] + bz1)); \
        float zg = __builtin_amdgcn_rcpf(1.f + ez); \
        float nn = cI[i] + bgi1 + rg * (cG[i] + bgn1); \
        float e2 = __expf(2.f * nn); \
        float ng = 1.f - 2.f * __builtin_amdgcn_rcpf(e2 + 1.f); \
        float hn = ng + zg * (hs1[rt][i] - ng); \
        hs1[rt][i] = hn; \
        const int Rw = (rt << 4) + (g << 2) + i; \
        *(unsigned short*)(smem + 16384 + ((PR)^8192) + (Rw << 8) + (((hc >> 3) ^ (Rw & 15)) << 4) + ((hc & 7) << 1)) = f2h(hn); \
      } \
    } \
  } \
} while (0)

__global__ __launch_bounds__(512, 2) void k_gru(
    const float* __restrict__ x,
    const uint4* __restrict__ pack,
    const float* __restrict__ bih0, const float* __restrict__ bhh0,
    const float* __restrict__ bih1, const float* __restrict__ bhh1,
    float* __restrict__ hidden)
{
    extern __shared__ char smem[];
    // [0,16384): h0[2][32][128]f16  [16384,32768): h1[2]  [32768,65024): x[63][32]x16B
    const int tid = threadIdx.x;
    const int lane = tid & 63;
    const int j = tid >> 6;             // wave index = hidden col group
    const int xr = lane & 15;
    const int g = lane >> 4;
    const int hc = (j << 4) + xr;       // D-fragment col (hidden unit)
    const int n0 = blockIdx.x << 5;

    // x preload: cell (r,t) = 6 fp16 + 2 zero pads, at 32768 + t*512 + r*16
    for (int c = tid; c < 32 * 60; c += 512) {
        int r = c / 60, t = c % 60;
        const float* xp = x + (size_t)(n0 + r) * (T_ * DF) + t * DF;
        u32 w0 = (u32)f2h(xp[0]) | ((u32)f2h(xp[1]) << 16);
        u32 w1 = (u32)f2h(xp[2]) | ((u32)f2h(xp[3]) << 16);
        u32 w2 = (u32)f2h(xp[4]) | ((u32)f2h(xp[5]) << 16);
        *(uint4*)(smem + 32768 + t * 512 + r * 16) = make_uint4(w0, w1, w2, 0u);
    }
    // zero x pad rows 60..62 and both parities of h buffers
    for (int i = tid; i < 384; i += 512) ((u32*)(smem + 32768 + 30720))[i] = 0u;
    for (int i = tid; i < 4096; i += 512) {
        ((u32*)smem)[i] = 0u;
        ((u32*)(smem + 16384))[i] = 0u;
    }

    uint4 wv[39];
#pragma unroll
    for (int s = 0; s < 39; ++s) wv[s] = pack[((j * 39 + s) << 6) + lane];

    const float br0 = bih0[hc] + bhh0[hc];
    const float bz0 = bih0[H + hc] + bhh0[H + hc];
    const float bgn0 = bhh0[2 * H + hc];
    const float bgi0 = bih0[2 * H + hc];
    const float br1 = bih1[hc] + bhh1[hc];
    const float bz1 = bih1[H + hc] + bhh1[H + hc];
    const float bgn1 = bhh1[2 * H + hc];
    const float bgi1 = bih1[2 * H + hc];

    float hs0[2][4] = {{0.f,0.f,0.f,0.f},{0.f,0.f,0.f,0.f}};
    float hs1[2][4] = {{0.f,0.f,0.f,0.f},{0.f,0.f,0.f,0.f}};

    // loop-invariant x fragment bases (advance 1024 B per unrolled pair)
    const char* xp0 = smem + 32768 + (g << 9) + (xr << 4);   // rt=0 row
    const char* xp1 = xp0 + 256;                             // rt=1 row

    __syncthreads();

    // t = 0 (even parity, L0 only)
    GRU_STEP(0, 1, 0, xp0, xp1);
    __syncthreads();
    // pairs t = 2tb+1 (odd), 2tb+2 (even), tb = 0..28  -> t = 1..58
    for (int tb = 0; tb < 29; ++tb) {
        GRU_STEP(8192, 1, 1, xp0 + 512, xp1 + 512);
        __syncthreads();
        GRU_STEP(0, 1, 1, xp0 + 1024, xp1 + 1024);
        __syncthreads();
        xp0 += 1024; xp1 += 1024;
    }
    // t = 59 (odd)
    GRU_STEP(8192, 1, 1, xp0 + 512, xp1 + 512);
    __syncthreads();
    // t = 60 (even, L1 only; x operand unused)
    GRU_STEP(0, 0, 1, xp0, xp1);

#pragma unroll
    for (int rt = 0; rt < 2; ++rt)
#pragma unroll
        for (int i = 0; i < 4; ++i) {
            int Rw = (rt << 4) + (g << 2) + i;
            hidden[(size_t)(n0 + Rw) * H + hc] = hs1[rt][i];
        }
}

// ------------------------------------------------------------------ epilogue
__global__ void k_rowstats(const float* __restrict__ hidden, const float* __restrict__ GH,
                           const float* __restrict__ wv1, const float* __restrict__ cc,
                           float* __restrict__ sx, float* __restrict__ invdv)
{
    int lane = threadIdx.x & 63;
    int wv = threadIdx.x >> 6;
    int n = blockIdx.x * 4 + wv;
    float p = hidden[(size_t)n * H + lane] * wv1[lane]
            + hidden[(size_t)n * H + 64 + lane] * wv1[64 + lane];
    float g = (lane < E_) ? GH[(size_t)n * E_ + lane] : 0.f;
#pragma unroll
    for (int off = 32; off > 0; off >>= 1) {
        p += __shfl_down(p, off);
        g += __shfl_down(g, off);
    }
    if (lane == 0) {
        sx[n] = p + cc[0];
        float dv = 0.5f * g;
        invdv[n] = (dv != 0.f) ? 1.f / dv : 0.f;
    }
}

// 256 blocks x 32 rows
__global__ void k_agg(const float* __restrict__ hidden, const float* __restrict__ GH,
                      float* __restrict__ agg, float* __restrict__ de)
{
    int t = threadIdx.x;
    int nbase = blockIdx.x * 32;
    if (t < H) {
        float part[E_];
#pragma unroll
        for (int e = 0; e < E_; ++e) part[e] = 0.f;
        for (int r = 0; r < 32; ++r) {
            int n = nbase + r;
            float hv = hidden[(size_t)n * H + t];
#pragma unroll
            for (int e = 0; e < E_; ++e) part[e] += GH[(size_t)n * E_ + e] * hv;
        }
#pragma unroll
        for (int e = 0; e < E_; ++e) atomicAdd(&agg[e * H + t], part[e]);
    } else if (t < H + E_) {
        int e = t - H;
        float s = 0.f;
        for (int r = 0; r < 32; ++r) s += GH[(size_t)(nbase + r) * E_ + e];
        atomicAdd(&de[e], s);
    }
}

__global__ void k_sy(const float* __restrict__ agg, const float* __restrict__ wv2,
                     const float* __restrict__ cc, const float* __restrict__ de,
                     float* __restrict__ sy, float* __restrict__ invde)
{
    int e = threadIdx.x;
    if (e < E_) {
        float s = 0.f;
        for (int h = 0; h < H; ++h) s += agg[e * H + h] * wv2[h];
        sy[e] = s + cc[1];
        float d = de[e];
        invde[e] = (d != 0.f) ? 1.f / d : 0.f;
    }
}

// 256 blocks x 32 rows, one barrier; invdv folded into att
__global__ void k_attS(const float* __restrict__ hidden, const float* __restrict__ sx,
                       const float* __restrict__ sy, const float* __restrict__ invdv,
                       float* __restrict__ S)
{
    __shared__ float att_s[32][E_];
    __shared__ float sy_s[E_];
    int t = threadIdx.x;
    if (t < E_) sy_s[t] = sy[t];
    __syncthreads();
    int nbase = blockIdx.x * 32;
    if (t < 32) {
        int n = nbase + t;
        float sxn = sx[n];
        float vv[E_];
        float m = -1e30f;
#pragma unroll
        for (int e = 0; e < E_; ++e) {
            float v = sxn + sy_s[e];
            v = (v >= 0.f) ? v : 0.01f * v;
            vv[e] = v;
            m = fmaxf(m, v);
        }
        float ss = 0.f;
#pragma unroll
        for (int e = 0; e < E_; ++e) { vv[e] = __expf(vv[e] - m); ss += vv[e]; }
        float sc = invdv[n] / ss;
#pragma unroll
        for (int e = 0; e < E_; ++e) att_s[t][e] = vv[e] * sc;
    }
    __syncthreads();
    if (t < H) {
        float part[E_];
#pragma unroll
        for (int e = 0; e < E_; ++e) part[e] = 0.f;
        for (int r = 0; r < 32; ++r) {
            float hv = hidden[(size_t)(nbase + r) * H + t];
#pragma unroll
            for (int e = 0; e < E_; ++e) part[e] += att_s[r][e] * hv;
        }
#pragma unroll
        for (int e = 0; e < E_; ++e) atomicAdd(&S[e * H + t], part[e]);
    }
}

// 256 blocks x 256 threads; wave-per-row, 8 rows per wave
__global__ __launch_bounds__(256) void k_final(
    const float* __restrict__ hidden, const float* __restrict__ sx,
    const float* __restrict__ sy, const float* __restrict__ invdv,
    const float* __restrict__ invde, const float* __restrict__ S,
    const float* __restrict__ WfcT, const float* __restrict__ bfc,
    const float* __restrict__ Wout, const float* __restrict__ bout,
    float* __restrict__ out)
{
    __shared__ float S_s[E_ * H];
    __shared__ float sy_s[E_], ide_s[E_];
    __shared__ float nh[4][H];
    int t = threadIdx.x;
    for (int i = t; i < E_ * H; i += 256) S_s[i] = S[i];
    if (t < E_) { sy_s[t] = sy[t]; ide_s[t] = invde[t]; }
    __syncthreads();
    int wv = t >> 6, lane = t & 63;
    float wouta = Wout[lane], woutb = Wout[64 + lane];
    float bfca = bfc[lane], bfcb = bfc[64 + lane];
    float boutv = bout[0];
    for (int it = 0; it < 8; ++it) {
        int n = blockIdx.x * 32 + it * 4 + wv;
        float sxn = sx[n];
        float idv = invdv[n];
        float vv[E_];
        float m = -1e30f;
#pragma unroll
        for (int e = 0; e < E_; ++e) {
            float v = sxn + sy_s[e];
            v = (v >= 0.f) ? v : 0.01f * v;
            vv[e] = v;
            m = fmaxf(m, v);
        }
        float ss = 0.f;
#pragma unroll
        for (int e = 0; e < E_; ++e) { vv[e] = __expf(vv[e] - m); ss += vv[e]; }
        float sc = idv / ss;
        float a0 = hidden[(size_t)n * H + lane];
        float a1 = hidden[(size_t)n * H + 64 + lane];
#pragma unroll
        for (int e = 0; e < E_; ++e) {
            float wgt = vv[e] * sc * ide_s[e];
            a0 += wgt * S_s[e * H + lane];
            a1 += wgt * S_s[e * H + 64 + lane];
        }
        nh[wv][lane] = a0;
        nh[wv][64 + lane] = a1;
        __syncthreads();
        float f0 = bfca, f1 = bfcb;
        for (int h = 0; h < H; h += 4) {
            float4 nv = *(const float4*)&nh[wv][h];
            f0 += nv.x * WfcT[(h + 0) * H + lane] + nv.y * WfcT[(h + 1) * H + lane]
                + nv.z * WfcT[(h + 2) * H + lane] + nv.w * WfcT[(h + 3) * H + lane];
            f1 += nv.x * WfcT[(h + 0) * H + 64 + lane] + nv.y * WfcT[(h + 1) * H + 64 + lane]
                + nv.z * WfcT[(h + 2) * H + 64 + lane] + nv.w * WfcT[(h + 3) * H + 64 + lane];
        }
        f0 = (f0 >= 0.f) ? f0 : 0.01f * f0;
        f1 = (f1 >= 0.f) ? f1 : 0.01f * f1;
        float op = f0 * wouta + f1 * woutb;
#pragma unroll
        for (int off = 32; off > 0; off >>= 1) op += __shfl_down(op, off);
        if (lane == 0) out[n] = op + boutv;
        __syncthreads();
    }
}

// ------------------------------------------------------------------ launcher
extern "C" void kernel_launch(void* const* d_in, const int* in_sizes, int n_in,
                              void* d_out, int out_size, void* d_ws, size_t ws_size,
                              hipStream_t stream)
{
    const float* x    = (const float*)d_in[0];
    const float* GH   = (const float*)d_in[1];
    const float* Wih0 = (const float*)d_in[2];
    const float* Whh0 = (const float*)d_in[3];
    const float* bih0 = (const float*)d_in[4];
    const float* bhh0 = (const float*)d_in[5];
    const float* Wih1 = (const float*)d_in[6];
    const float* Whh1 = (const float*)d_in[7];
    const float* bih1 = (const float*)d_in[8];
    const float* bhh1 = (const float*)d_in[9];
    const float* Wt   = (const float*)d_in[10];
    const float* bt   = (const float*)d_in[11];
    const float* a    = (const float*)d_in[12];
    const float* Wfc  = (const float*)d_in[13];
    const float* bfc  = (const float*)d_in[14];
    const float* Wout = (const float*)d_in[15];
    const float* bout = (const float*)d_in[16];

    float* ws    = (float*)d_ws;
    uint4* pack  = (uint4*)(ws + OFF_PACK);
    float* WfcT  = ws + OFF_WFCT;
    float* hid   = ws + OFF_HID;
    float* sx    = ws + OFF_SX;
    float* idv   = ws + OFF_IDV;
    float* agg   = ws + OFF_AGG;
    float* de    = ws + OFF_DE;
    float* S     = ws + OFF_S;
    float* ide   = ws + OFF_IDE;
    float* sy    = ws + OFF_SY;
    float* cc    = ws + OFF_CC;
    float* wv1   = ws + OFF_WV1;
    float* wv2   = ws + OFF_WV2;

    k_pack<<<78, 256, 0, stream>>>(Wih0, Whh0, Wih1, Whh1, pack);
    k_prep_fc<<<64, 256, 0, stream>>>(Wfc, WfcT);
    k_prep_wv<<<1, 128, 0, stream>>>(Wt, bt, a, wv1, wv2, cc);
    k_zero<<<31, 256, 0, stream>>>(agg);

    const size_t lds_bytes = 65024;
    (void)hipFuncSetAttribute((const void*)k_gru,
                              hipFuncAttributeMaxDynamicSharedMemorySize,
                              (int)lds_bytes);
    k_gru<<<256, 512, lds_bytes, stream>>>(x, pack, bih0, bhh0, bih1, bhh1, hid);

    k_rowstats<<<2048, 256, 0, stream>>>(hid, GH, wv1, cc, sx, idv);
    k_agg<<<256, 256, 0, stream>>>(hid, GH, agg, de);
    k_sy<<<1, 64, 0, stream>>>(agg, wv2, cc, de, sy, ide);
    k_attS<<<256, 256, 0, stream>>>(hid, sx, sy, idv, S);
    k_final<<<256, 256, 0, stream>>>(hid, sx, sy, idv, ide, S, WfcT, bfc,
                                     Wout, bout, (float*)d_out);
}

// Round 6
// 284.710 us; speedup vs baseline: 22.8723x; 1.1722x over previous
//
#include <hip/hip_runtime.h>
#include <hip/hip_fp16.h>
#include <cstddef>

#define H 128
#define E_ 30
#define T_ 60
#define DF 6

typedef unsigned int u32;
typedef __attribute__((ext_vector_type(8))) short short8;
typedef __attribute__((ext_vector_type(4))) float f32x4;

// ---- workspace layout (float offsets) ----
#define OFF_PACK   0          // uint4[8*39*64] fp16 weights
#define OFF_WFCT   79872      // Wfc^T [128][128]
#define OFF_HID    96256      // hidden [8192][128]
#define OFF_SX     1144832
#define OFF_IDV    1153024
#define OFF_AGG    1161216
#define OFF_DE     1165056
#define OFF_S      1165088
#define OFF_IDE    1168928
#define OFF_SY     1168960
#define OFF_CC     1168992
#define OFF_WV1    1169024
#define OFF_WV2    1169152
#define ZERO_CNT   7712       // agg+de+S contiguous

__device__ __forceinline__ unsigned short f2h(float f) {
    return __half_as_ushort(__float2half(f));
}

// ------------------------------------------------------------------ weight packing (fp16)
// B-fragment order for mfma_f32_16x16x32_f16: lane l holds B[k][c] with
// c = hc0 + (l&15), k = kt*32 + 8*(l>>4) + i  (8 consecutive k per lane).
// Slots per hc-group j (39 total):
//  L0: s0-4 r (K=160: h0|x|pad), s5-9 z, s10-13 ghn (K=128), s14 gin (x, Kpad32)
//  L1: s15-22 r (K=256: y|h1), s23-30 z, s31-34 ghn (h1), s35-38 gin (y)
__global__ void k_pack(const float* __restrict__ Wih0, const float* __restrict__ Whh0,
                       const float* __restrict__ Wih1, const float* __restrict__ Whh1,
                       uint4* __restrict__ pack)
{
    int u = blockIdx.x * 256 + threadIdx.x;   // 78*256 = 19968 exact
    int lane = u & 63;
    int s = (u >> 6) % 39;
    int j = (u >> 6) / 39;
    int hc = j * 16 + (lane & 15);
    int g = lane >> 4;
    int layer, gate, kt;
    if (s < 5)       { layer = 0; gate = 0; kt = s; }
    else if (s < 10) { layer = 0; gate = 1; kt = s - 5; }
    else if (s < 14) { layer = 0; gate = 2; kt = s - 10; }
    else if (s < 15) { layer = 0; gate = 3; kt = 0; }
    else if (s < 23) { layer = 1; gate = 0; kt = s - 15; }
    else if (s < 31) { layer = 1; gate = 1; kt = s - 23; }
    else if (s < 35) { layer = 1; gate = 2; kt = s - 31; }
    else             { layer = 1; gate = 3; kt = s - 35; }

    u32 wd[4];
    for (int p = 0; p < 4; ++p) {
        unsigned short hh[2];
        for (int q = 0; q < 2; ++q) {
            int k = kt * 32 + g * 8 + p * 2 + q;
            float v = 0.f;
            if (layer == 0) {
                if (gate <= 1) {
                    int row = gate * 128 + hc;
                    if (k < 128) v = Whh0[row * 128 + k];
                    else if (k < 134) v = Wih0[row * 6 + (k - 128)];
                } else if (gate == 2) {
                    v = Whh0[(256 + hc) * 128 + k];
                } else {
                    if (k < 6) v = Wih0[(256 + hc) * 6 + k];
                }
            } else {
                if (gate <= 1) {
                    int row = gate * 128 + hc;
                    v = (k < 128) ? Wih1[row * 128 + k] : Whh1[row * 128 + (k - 128)];
                } else if (gate == 2) {
                    v = Whh1[(256 + hc) * 128 + k];
                } else {
                    v = Wih1[(256 + hc) * 128 + k];
                }
            }
            hh[q] = f2h(v);
        }
        wd[p] = (u32)hh[0] | ((u32)hh[1] << 16);
    }
    pack[(j * 39 + s) * 64 + lane] = make_uint4(wd[0], wd[1], wd[2], wd[3]);
}

__global__ void k_prep_fc(const float* __restrict__ Wfc, float* __restrict__ WfcT)
{
    int i = blockIdx.x * 256 + threadIdx.x;   // 64*256 = 16384
    int col = i / 128, h = i % 128;
    WfcT[h * 128 + col] = Wfc[i];
}

__global__ void k_prep_wv(const float* __restrict__ Wt, const float* __restrict__ bt,
                          const float* __restrict__ a, float* __restrict__ wv1,
                          float* __restrict__ wv2, float* __restrict__ cc)
{
    int i = threadIdx.x;  // 0..127
    float s1 = 0.f, s2 = 0.f;
    for (int j = 0; j < H; ++j) {
        float w = Wt[(size_t)j * H + i];
        s1 += w * a[j];
        s2 += w * a[H + j];
    }
    wv1[i] = s1;
    wv2[i] = s2;
    if (i == 0) {
        float c1 = 0.f, c2 = 0.f;
        for (int j = 0; j < H; ++j) { c1 += bt[j] * a[j]; c2 += bt[j] * a[H + j]; }
        cc[0] = c1; cc[1] = c2;
    }
}

__global__ void k_zero(float* __restrict__ z)
{
    int i = blockIdx.x * 256 + threadIdx.x;
    if (i < ZERO_CNT) z[i] = 0.f;
}

// ------------------------------------------------------------------ fused 2-layer GRU (MFMA fp16)
// Skewed pipeline: phase t computes L0(t) AND L1(t-1) with ONE barrier.
// Single loop body with wave-uniform guards (R4 structure: no spill, 7MB
// FETCH) + v_rcp_f32 activations (R5's keeper: no precise-divide sequences).
#define MFMA16 __builtin_amdgcn_mfma_f32_16x16x32_f16

__global__ __launch_bounds__(512, 2) void k_gru(
    const float* __restrict__ x,
    const uint4* __restrict__ pack,
    const float* __restrict__ bih0, const float* __restrict__ bhh0,
    const float* __restrict__ bih1, const float* __restrict__ bhh1,
    float* __restrict__ hidden)
{
    extern __shared__ char smem[];
    // [0,16384): h0[2][32][128]f16  [16384,32768): h1[2]  [32768,65024): x[63][32]x16B
    const int tid = threadIdx.x;
    const int lane = tid & 63;
    const int j = tid >> 6;             // wave index = hidden col group
    const int xr = lane & 15;
    const int g = lane >> 4;
    const int hc = (j << 4) + xr;       // D-fragment col (hidden unit)
    const int n0 = blockIdx.x << 5;

    // x preload: cell (r,t) = 6 fp16 + 2 zero pads, at 32768 + t*512 + r*16
    for (int c = tid; c < 32 * 60; c += 512) {
        int r = c / 60, t = c % 60;
        const float* xp = x + (size_t)(n0 + r) * (T_ * DF) + t * DF;
        u32 w0 = (u32)f2h(xp[0]) | ((u32)f2h(xp[1]) << 16);
        u32 w1 = (u32)f2h(xp[2]) | ((u32)f2h(xp[3]) << 16);
        u32 w2 = (u32)f2h(xp[4]) | ((u32)f2h(xp[5]) << 16);
        *(uint4*)(smem + 32768 + t * 512 + r * 16) = make_uint4(w0, w1, w2, 0u);
    }
    // zero x pad rows 60..62 and both parities of h buffers
    for (int i = tid; i < 384; i += 512) ((u32*)(smem + 32768 + 30720))[i] = 0u;
    for (int i = tid; i < 4096; i += 512) {
        ((u32*)smem)[i] = 0u;
        ((u32*)(smem + 16384))[i] = 0u;
    }

    uint4 wv[39];
#pragma unroll
    for (int s = 0; s < 39; ++s) wv[s] = pack[((j * 39 + s) << 6) + lane];

    const float br0 = bih0[hc] + bhh0[hc];
    const float bz0 = bih0[H + hc] + bhh0[H + hc];
    const float bgn0 = bhh0[2 * H + hc];
    const float bgi0 = bih0[2 * H + hc];
    const float br1 = bih1[hc] + bhh1[hc];
    const float bz1 = bih1[H + hc] + bhh1[H + hc];
    const float bgn1 = bhh1[2 * H + hc];
    const float bgi1 = bih1[2 * H + hc];

    float hs0[2][4] = {{0.f,0.f,0.f,0.f},{0.f,0.f,0.f,0.f}};
    float hs1[2][4] = {{0.f,0.f,0.f,0.f},{0.f,0.f,0.f,0.f}};

    // loop-invariant x fragment base (rt=1 row = +256 const offset)
    const char* xbase = smem + 32768 + (g << 9) + (xr << 4);

    __syncthreads();

    for (int t = 0; t <= T_; ++t) {
        const int pr  = (t & 1) << 13;   // h0 write / h1 read parity (byte)
        const int prx = pr ^ 8192;       // h0 read / h1 write parity

#pragma unroll
        for (int rt = 0; rt < 2; ++rt) {
            const int R = (rt << 4) + xr;
            const int rowb = R << 8;

            // f0 = h0(t-1) fragments — shared by L0(t) and L1(t-1)
            uint4 f0[4];
#pragma unroll
            for (int kt = 0; kt < 4; ++kt)
                f0[kt] = *(const uint4*)(smem + prx + rowb + ((((kt << 2) | g) ^ xr) << 4));

            f32x4 aR = {0,0,0,0}, aZ = {0,0,0,0}, aG = {0,0,0,0}, aI = {0,0,0,0};
            f32x4 cR = {0,0,0,0}, cZ = {0,0,0,0}, cG = {0,0,0,0}, cI = {0,0,0,0};

            if (t < T_) {
                uint4 fx = *(const uint4*)(xbase + (size_t)t * 512 + rt * 256);
                short8 xv = __builtin_bit_cast(short8, fx);
#pragma unroll
                for (int kt = 0; kt < 4; ++kt) {
                    short8 av = __builtin_bit_cast(short8, f0[kt]);
                    aR = MFMA16(av, __builtin_bit_cast(short8, wv[kt]), aR, 0, 0, 0);
                    aZ = MFMA16(av, __builtin_bit_cast(short8, wv[5 + kt]), aZ, 0, 0, 0);
                    aG = MFMA16(av, __builtin_bit_cast(short8, wv[10 + kt]), aG, 0, 0, 0);
                }
                aR = MFMA16(xv, __builtin_bit_cast(short8, wv[4]), aR, 0, 0, 0);
                aZ = MFMA16(xv, __builtin_bit_cast(short8, wv[9]), aZ, 0, 0, 0);
                aI = MFMA16(xv, __builtin_bit_cast(short8, wv[14]), aI, 0, 0, 0);
            }

            if (t > 0) {
                // y-part of L1(t-1): reuse f0
#pragma unroll
                for (int kt = 0; kt < 4; ++kt) {
                    short8 av = __builtin_bit_cast(short8, f0[kt]);
                    cR = MFMA16(av, __builtin_bit_cast(short8, wv[15 + kt]), cR, 0, 0, 0);
                    cZ = MFMA16(av, __builtin_bit_cast(short8, wv[23 + kt]), cZ, 0, 0, 0);
                    cI = MFMA16(av, __builtin_bit_cast(short8, wv[35 + kt]), cI, 0, 0, 0);
                }
                // h1-part: f1 = h1(t-2)
#pragma unroll
                for (int kt = 0; kt < 4; ++kt) {
                    uint4 f1 = *(const uint4*)(smem + 16384 + pr + rowb + ((((kt << 2) | g) ^ xr) << 4));
                    short8 bv = __builtin_bit_cast(short8, f1);
                    cR = MFMA16(bv, __builtin_bit_cast(short8, wv[19 + kt]), cR, 0, 0, 0);
                    cZ = MFMA16(bv, __builtin_bit_cast(short8, wv[27 + kt]), cZ, 0, 0, 0);
                    cG = MFMA16(bv, __builtin_bit_cast(short8, wv[31 + kt]), cG, 0, 0, 0);
                }
            }

            if (t < T_) {
#pragma unroll
                for (int i = 0; i < 4; ++i) {
                    float rg = __builtin_amdgcn_rcpf(1.f + __expf(-(aR[i] + br0)));
                    float zg = __builtin_amdgcn_rcpf(1.f + __expf(-(aZ[i] + bz0)));
                    float nn = aI[i] + bgi0 + rg * (aG[i] + bgn0);
                    float e2 = __expf(2.f * nn);
                    float ng = 1.f - 2.f * __builtin_amdgcn_rcpf(e2 + 1.f);
                    float hn = ng + zg * (hs0[rt][i] - ng);
                    hs0[rt][i] = hn;
                    int Rw = (rt << 4) + (g << 2) + i;
                    *(unsigned short*)(smem + pr + (Rw << 8) + (((hc >> 3) ^ (Rw & 15)) << 4) + ((hc & 7) << 1)) = f2h(hn);
                }
            }
            if (t > 0) {
#pragma unroll
                for (int i = 0; i < 4; ++i) {
                    float rg = __builtin_amdgcn_rcpf(1.f + __expf(-(cR[i] + br1)));
                    float zg = __builtin_amdgcn_rcpf(1.f + __expf(-(cZ[i] + bz1)));
                    float nn = cI[i] + bgi1 + rg * (cG[i] + bgn1);
                    float e2 = __expf(2.f * nn);
                    float ng = 1.f - 2.f * __builtin_amdgcn_rcpf(e2 + 1.f);
                    float hn = ng + zg * (hs1[rt][i] - ng);
                    hs1[rt][i] = hn;
                    int Rw = (rt << 4) + (g << 2) + i;
                    *(unsigned short*)(smem + 16384 + prx + (Rw << 8) + (((hc >> 3) ^ (Rw & 15)) << 4) + ((hc & 7) << 1)) = f2h(hn);
                }
            }
        }
        __syncthreads();
    }

#pragma unroll
    for (int rt = 0; rt < 2; ++rt)
#pragma unroll
        for (int i = 0; i < 4; ++i) {
            int Rw = (rt << 4) + (g << 2) + i;
            hidden[(size_t)(n0 + Rw) * H + hc] = hs1[rt][i];
        }
}

// ------------------------------------------------------------------ epilogue
__global__ void k_rowstats(const float* __restrict__ hidden, const float* __restrict__ GH,
                           const float* __restrict__ wv1, const float* __restrict__ cc,
                           float* __restrict__ sx, float* __restrict__ invdv)
{
    int lane = threadIdx.x & 63;
    int wv = threadIdx.x >> 6;
    int n = blockIdx.x * 4 + wv;
    float p = hidden[(size_t)n * H + lane] * wv1[lane]
            + hidden[(size_t)n * H + 64 + lane] * wv1[64 + lane];
    float g = (lane < E_) ? GH[(size_t)n * E_ + lane] : 0.f;
#pragma unroll
    for (int off = 32; off > 0; off >>= 1) {
        p += __shfl_down(p, off);
        g += __shfl_down(g, off);
    }
    if (lane == 0) {
        sx[n] = p + cc[0];
        float dv = 0.5f * g;
        invdv[n] = (dv != 0.f) ? 1.f / dv : 0.f;
    }
}

// 256 blocks x 32 rows
__global__ void k_agg(const float* __restrict__ hidden, const float* __restrict__ GH,
                      float* __restrict__ agg, float* __restrict__ de)
{
    int t = threadIdx.x;
    int nbase = blockIdx.x * 32;
    if (t < H) {
        float part[E_];
#pragma unroll
        for (int e = 0; e < E_; ++e) part[e] = 0.f;
        for (int r = 0; r < 32; ++r) {
            int n = nbase + r;
            float hv = hidden[(size_t)n * H + t];
#pragma unroll
            for (int e = 0; e < E_; ++e) part[e] += GH[(size_t)n * E_ + e] * hv;
        }
#pragma unroll
        for (int e = 0; e < E_; ++e) atomicAdd(&agg[e * H + t], part[e]);
    } else if (t < H + E_) {
        int e = t - H;
        float s = 0.f;
        for (int r = 0; r < 32; ++r) s += GH[(size_t)(nbase + r) * E_ + e];
        atomicAdd(&de[e], s);
    }
}

__global__ void k_sy(const float* __restrict__ agg, const float* __restrict__ wv2,
                     const float* __restrict__ cc, const float* __restrict__ de,
                     float* __restrict__ sy, float* __restrict__ invde)
{
    int e = threadIdx.x;
    if (e < E_) {
        float s = 0.f;
        for (int h = 0; h < H; ++h) s += agg[e * H + h] * wv2[h];
        sy[e] = s + cc[1];
        float d = de[e];
        invde[e] = (d != 0.f) ? 1.f / d : 0.f;
    }
}

// 256 blocks x 32 rows, one barrier; invdv folded into att
__global__ void k_attS(const float* __restrict__ hidden, const float* __restrict__ sx,
                       const float* __restrict__ sy, const float* __restrict__ invdv,
                       float* __restrict__ S)
{
    __shared__ float att_s[32][E_];
    __shared__ float sy_s[E_];
    int t = threadIdx.x;
    if (t < E_) sy_s[t] = sy[t];
    __syncthreads();
    int nbase = blockIdx.x * 32;
    if (t < 32) {
        int n = nbase + t;
        float sxn = sx[n];
        float vv[E_];
        float m = -1e30f;
#pragma unroll
        for (int e = 0; e < E_; ++e) {
            float v = sxn + sy_s[e];
            v = (v >= 0.f) ? v : 0.01f * v;
            vv[e] = v;
            m = fmaxf(m, v);
        }
        float ss = 0.f;
#pragma unroll
        for (int e = 0; e < E_; ++e) { vv[e] = __expf(vv[e] - m); ss += vv[e]; }
        float sc = invdv[n] / ss;
#pragma unroll
        for (int e = 0; e < E_; ++e) att_s[t][e] = vv[e] * sc;
    }
    __syncthreads();
    if (t < H) {
        float part[E_];
#pragma unroll
        for (int e = 0; e < E_; ++e) part[e] = 0.f;
        for (int r = 0; r < 32; ++r) {
            float hv = hidden[(size_t)(nbase + r) * H + t];
#pragma unroll
            for (int e = 0; e < E_; ++e) part[e] += att_s[r][e] * hv;
        }
#pragma unroll
        for (int e = 0; e < E_; ++e) atomicAdd(&S[e * H + t], part[e]);
    }
}

// 256 blocks x 256 threads; wave-per-row, 8 rows per wave
__global__ __launch_bounds__(256) void k_final(
    const float* __restrict__ hidden, const float* __restrict__ sx,
    const float* __restrict__ sy, const float* __restrict__ invdv,
    const float* __restrict__ invde, const float* __restrict__ S,
    const float* __restrict__ WfcT, const float* __restrict__ bfc,
    const float* __restrict__ Wout, const float* __restrict__ bout,
    float* __restrict__ out)
{
    __shared__ float S_s[E_ * H];
    __shared__ float sy_s[E_], ide_s[E_];
    __shared__ float nh[4][H];
    int t = threadIdx.x;
    for (int i = t; i < E_ * H; i += 256) S_s[i] = S[i];
    if (t < E_) { sy_s[t] = sy[t]; ide_s[t] = invde[t]; }
    __syncthreads();
    int wv = t >> 6, lane = t & 63;
    float wouta = Wout[lane], woutb = Wout[64 + lane];
    float bfca = bfc[lane], bfcb = bfc[64 + lane];
    float boutv = bout[0];
    for (int it = 0; it < 8; ++it) {
        int n = blockIdx.x * 32 + it * 4 + wv;
        float sxn = sx[n];
        float idv = invdv[n];
        float vv[E_];
        float m = -1e30f;
#pragma unroll
        for (int e = 0; e < E_; ++e) {
            float v = sxn + sy_s[e];
            v = (v >= 0.f) ? v : 0.01f * v;
            vv[e] = v;
            m = fmaxf(m, v);
        }
        float ss = 0.f;
#pragma unroll
        for (int e = 0; e < E_; ++e) { vv[e] = __expf(vv[e] - m); ss += vv[e]; }
        float sc = idv / ss;
        float a0 = hidden[(size_t)n * H + lane];
        float a1 = hidden[(size_t)n * H + 64 + lane];
#pragma unroll
        for (int e = 0; e < E_; ++e) {
            float wgt = vv[e] * sc * ide_s[e];
            a0 += wgt * S_s[e * H + lane];
            a1 += wgt * S_s[e * H + 64 + lane];
        }
        nh[wv][lane] = a0;
        nh[wv][64 + lane] = a1;
        __syncthreads();
        float f0 = bfca, f1 = bfcb;
        for (int h = 0; h < H; h += 4) {
            float4 nv = *(const float4*)&nh[wv][h];
            f0 += nv.x * WfcT[(h + 0) * H + lane] + nv.y * WfcT[(h + 1) * H + lane]
                + nv.z * WfcT[(h + 2) * H + lane] + nv.w * WfcT[(h + 3) * H + lane];
            f1 += nv.x * WfcT[(h + 0) * H + 64 + lane] + nv.y * WfcT[(h + 1) * H + 64 + lane]
                + nv.z * WfcT[(h + 2) * H + 64 + lane] + nv.w * WfcT[(h + 3) * H + 64 + lane];
        }
        f0 = (f0 >= 0.f) ? f0 : 0.01f * f0;
        f1 = (f1 >= 0.f) ? f1 : 0.01f * f1;
        float op = f0 * wouta + f1 * woutb;
#pragma unroll
        for (int off = 32; off > 0; off >>= 1) op += __shfl_down(op, off);
        if (lane == 0) out[n] = op + boutv;
        __syncthreads();
    }
}

// ------------------------------------------------------------------ launcher
extern "C" void kernel_launch(void* const* d_in, const int* in_sizes, int n_in,
                              void* d_out, int out_size, void* d_ws, size_t ws_size,
                              hipStream_t stream)
{
    const float* x    = (const float*)d_in[0];
    const float* GH   = (const float*)d_in[1];
    const float* Wih0 = (const float*)d_in[2];
    const float* Whh0 = (const float*)d_in[3];
    const float* bih0 = (const float*)d_in[4];
    const float* bhh0 = (const float*)d_in[5];
    const float* Wih1 = (const float*)d_in[6];
    const float* Whh1 = (const float*)d_in[7];
    const float* bih1 = (const float*)d_in[8];
    const float* bhh1 = (const float*)d_in[9];
    const float* Wt   = (const float*)d_in[10];
    const float* bt   = (const float*)d_in[11];
    const float* a    = (const float*)d_in[12];
    const float* Wfc  = (const float*)d_in[13];
    const float* bfc  = (const float*)d_in[14];
    const float* Wout = (const float*)d_in[15];
    const float* bout = (const float*)d_in[16];

    float* ws    = (float*)d_ws;
    uint4* pack  = (uint4*)(ws + OFF_PACK);
    float* WfcT  = ws + OFF_WFCT;
    float* hid   = ws + OFF_HID;
    float* sx    = ws + OFF_SX;
    float* idv   = ws + OFF_IDV;
    float* agg   = ws + OFF_AGG;
    float* de    = ws + OFF_DE;
    float* S     = ws + OFF_S;
    float* ide   = ws + OFF_IDE;
    float* sy    = ws + OFF_SY;
    float* cc    = ws + OFF_CC;
    float* wv1   = ws + OFF_WV1;
    float* wv2   = ws + OFF_WV2;

    k_pack<<<78, 256, 0, stream>>>(Wih0, Whh0, Wih1, Whh1, pack);
    k_prep_fc<<<64, 256, 0, stream>>>(Wfc, WfcT);
    k_prep_wv<<<1, 128, 0, stream>>>(Wt, bt, a, wv1, wv2, cc);
    k_zero<<<31, 256, 0, stream>>>(agg);

    const size_t lds_bytes = 65024;
    (void)hipFuncSetAttribute((const void*)k_gru,
                              hipFuncAttributeMaxDynamicSharedMemorySize,
                              (int)lds_bytes);
    k_gru<<<256, 512, lds_bytes, stream>>>(x, pack, bih0, bhh0, bih1, bhh1, hid);

    k_rowstats<<<2048, 256, 0, stream>>>(hid, GH, wv1, cc, sx, idv);
    k_agg<<<256, 256, 0, stream>>>(hid, GH, agg, de);
    k_sy<<<1, 64, 0, stream>>>(agg, wv2, cc, de, sy, ide);
    k_attS<<<256, 256, 0, stream>>>(hid, sx, sy, idv, S);
    k_final<<<256, 256, 0, stream>>>(hid, sx, sy, idv, ide, S, WfcT, bfc,
                                     Wout, bout, (float*)d_out);
}

// Round 7
// 244.376 us; speedup vs baseline: 26.6474x; 1.1651x over previous
//
#include <hip/hip_runtime.h>
#include <hip/hip_fp16.h>
#include <cstddef>

#define H 128
#define E_ 30
#define T_ 60
#define DF 6

typedef unsigned int u32;
typedef __attribute__((ext_vector_type(8))) short short8;
typedef __attribute__((ext_vector_type(4))) float f32x4;

// ---- workspace layout (float offsets) ----
#define OFF_PACK   0          // uint4[8*39*64] fp16 weights
#define OFF_WFCT   79872      // Wfc^T [128][128]
#define OFF_HID    96256      // hidden [8192][128]
#define OFF_SX     1144832
#define OFF_IDV    1153024
#define OFF_AGG    1161216
#define OFF_DE     1165056
#define OFF_S      1165088
#define OFF_IDE    1168928
#define OFF_SY     1168960
#define OFF_CC     1168992
#define OFF_WV1    1169024
#define OFF_WV2    1169152
#define ZERO_CNT   7712       // agg+de+S contiguous

__device__ __forceinline__ unsigned short f2h(float f) {
    return __half_as_ushort(__float2half(f));
}

// ------------------------------------------------------------------ weight packing (fp16)
// B-fragment order for mfma_f32_16x16x32_f16: lane l holds B[k][c] with
// c = hc0 + (l&15), k = kt*32 + 8*(l>>4) + i  (8 consecutive k per lane).
// Slots per hc-group j (39 total):
//  L0: s0-4 r (K=160: h0|x|pad), s5-9 z, s10-13 ghn (K=128), s14 gin (x, Kpad32)
//  L1: s15-22 r (K=256: y|h1), s23-30 z, s31-34 ghn (h1), s35-38 gin (y)
__global__ void k_pack(const float* __restrict__ Wih0, const float* __restrict__ Whh0,
                       const float* __restrict__ Wih1, const float* __restrict__ Whh1,
                       uint4* __restrict__ pack)
{
    int u = blockIdx.x * 256 + threadIdx.x;   // 78*256 = 19968 exact
    int lane = u & 63;
    int s = (u >> 6) % 39;
    int j = (u >> 6) / 39;
    int hc = j * 16 + (lane & 15);
    int g = lane >> 4;
    int layer, gate, kt;
    if (s < 5)       { layer = 0; gate = 0; kt = s; }
    else if (s < 10) { layer = 0; gate = 1; kt = s - 5; }
    else if (s < 14) { layer = 0; gate = 2; kt = s - 10; }
    else if (s < 15) { layer = 0; gate = 3; kt = 0; }
    else if (s < 23) { layer = 1; gate = 0; kt = s - 15; }
    else if (s < 31) { layer = 1; gate = 1; kt = s - 23; }
    else if (s < 35) { layer = 1; gate = 2; kt = s - 31; }
    else             { layer = 1; gate = 3; kt = s - 35; }

    u32 wd[4];
    for (int p = 0; p < 4; ++p) {
        unsigned short hh[2];
        for (int q = 0; q < 2; ++q) {
            int k = kt * 32 + g * 8 + p * 2 + q;
            float v = 0.f;
            if (layer == 0) {
                if (gate <= 1) {
                    int row = gate * 128 + hc;
                    if (k < 128) v = Whh0[row * 128 + k];
                    else if (k < 134) v = Wih0[row * 6 + (k - 128)];
                } else if (gate == 2) {
                    v = Whh0[(256 + hc) * 128 + k];
                } else {
                    if (k < 6) v = Wih0[(256 + hc) * 6 + k];
                }
            } else {
                if (gate <= 1) {
                    int row = gate * 128 + hc;
                    v = (k < 128) ? Wih1[row * 128 + k] : Whh1[row * 128 + (k - 128)];
                } else if (gate == 2) {
                    v = Whh1[(256 + hc) * 128 + k];
                } else {
                    v = Wih1[(256 + hc) * 128 + k];
                }
            }
            hh[q] = f2h(v);
        }
        wd[p] = (u32)hh[0] | ((u32)hh[1] << 16);
    }
    pack[(j * 39 + s) * 64 + lane] = make_uint4(wd[0], wd[1], wd[2], wd[3]);
}

__global__ void k_prep_fc(const float* __restrict__ Wfc, float* __restrict__ WfcT)
{
    int i = blockIdx.x * 256 + threadIdx.x;   // 64*256 = 16384
    int col = i / 128, h = i % 128;
    WfcT[h * 128 + col] = Wfc[i];
}

__global__ void k_prep_wv(const float* __restrict__ Wt, const float* __restrict__ bt,
                          const float* __restrict__ a, float* __restrict__ wv1,
                          float* __restrict__ wv2, float* __restrict__ cc)
{
    int i = threadIdx.x;  // 0..127
    float s1 = 0.f, s2 = 0.f;
    for (int j = 0; j < H; ++j) {
        float w = Wt[(size_t)j * H + i];
        s1 += w * a[j];
        s2 += w * a[H + j];
    }
    wv1[i] = s1;
    wv2[i] = s2;
    if (i == 0) {
        float c1 = 0.f, c2 = 0.f;
        for (int j = 0; j < H; ++j) { c1 += bt[j] * a[j]; c2 += bt[j] * a[H + j]; }
        cc[0] = c1; cc[1] = c2;
    }
}

__global__ void k_zero(float* __restrict__ z)
{
    int i = blockIdx.x * 256 + threadIdx.x;
    if (i < ZERO_CNT) z[i] = 0.f;
}

// ------------------------------------------------------------------ fused 2-layer GRU (MFMA fp16)
// Skewed pipeline, ONE barrier/step. Anti-spill structure: within each
// rt-tile the two layers run as SEQUENTIAL phases (L0 mfma+act, then L1
// mfma+act) separated by sched_barrier(0), so only ONE 16-reg accumulator
// set is live at a time. Peak regs ~224 < 256 cap (2 waves/SIMD).
#define MFMA16 __builtin_amdgcn_mfma_f32_16x16x32_f16

__global__ __launch_bounds__(512, 2) void k_gru(
    const float* __restrict__ x,
    const uint4* __restrict__ pack,
    const float* __restrict__ bih0, const float* __restrict__ bhh0,
    const float* __restrict__ bih1, const float* __restrict__ bhh1,
    float* __restrict__ hidden)
{
    extern __shared__ char smem[];
    // [0,16384): h0[2][32][128]f16  [16384,32768): h1[2]  [32768,65024): x[63][32]x16B
    const int tid = threadIdx.x;
    const int lane = tid & 63;
    const int j = tid >> 6;             // wave index = hidden col group
    const int xr = lane & 15;
    const int g = lane >> 4;
    const int hc = (j << 4) + xr;       // D-fragment col (hidden unit)
    const int n0 = blockIdx.x << 5;

    // x preload: cell (r,t) = 6 fp16 + 2 zero pads, at 32768 + t*512 + r*16
    for (int c = tid; c < 32 * 60; c += 512) {
        int r = c / 60, t = c % 60;
        const float* xp = x + (size_t)(n0 + r) * (T_ * DF) + t * DF;
        u32 w0 = (u32)f2h(xp[0]) | ((u32)f2h(xp[1]) << 16);
        u32 w1 = (u32)f2h(xp[2]) | ((u32)f2h(xp[3]) << 16);
        u32 w2 = (u32)f2h(xp[4]) | ((u32)f2h(xp[5]) << 16);
        *(uint4*)(smem + 32768 + t * 512 + r * 16) = make_uint4(w0, w1, w2, 0u);
    }
    // zero x pad rows 60..62 and both parities of h buffers
    for (int i = tid; i < 384; i += 512) ((u32*)(smem + 32768 + 30720))[i] = 0u;
    for (int i = tid; i < 4096; i += 512) {
        ((u32*)smem)[i] = 0u;
        ((u32*)(smem + 16384))[i] = 0u;
    }

    uint4 wv[39];
#pragma unroll
    for (int s = 0; s < 39; ++s) wv[s] = pack[((j * 39 + s) << 6) + lane];

    const float br0 = bih0[hc] + bhh0[hc];
    const float bz0 = bih0[H + hc] + bhh0[H + hc];
    const float bgn0 = bhh0[2 * H + hc];
    const float bgi0 = bih0[2 * H + hc];
    const float br1 = bih1[hc] + bhh1[hc];
    const float bz1 = bih1[H + hc] + bhh1[H + hc];
    const float bgn1 = bhh1[2 * H + hc];
    const float bgi1 = bih1[2 * H + hc];

    float hs0[2][4] = {{0.f,0.f,0.f,0.f},{0.f,0.f,0.f,0.f}};
    float hs1[2][4] = {{0.f,0.f,0.f,0.f},{0.f,0.f,0.f,0.f}};

    // loop-invariant x fragment base (rt=1 row = +256 const offset)
    const char* xbase = smem + 32768 + (g << 9) + (xr << 4);

    __syncthreads();

    for (int t = 0; t <= T_; ++t) {
        const int pr  = (t & 1) << 13;   // h0 write / h1 read parity (byte)
        const int prx = pr ^ 8192;       // h0 read / h1 write parity

#pragma unroll
        for (int rt = 0; rt < 2; ++rt) {
            const int R = (rt << 4) + xr;
            const int rowb = R << 8;

            // f0 = h0(t-1) fragments — shared by L0(t) and L1(t-1)
            uint4 f0[4];
#pragma unroll
            for (int kt = 0; kt < 4; ++kt)
                f0[kt] = *(const uint4*)(smem + prx + rowb + ((((kt << 2) | g) ^ xr) << 4));

            // ================= phase A: L0(t) complete =================
            if (t < T_) {
                f32x4 aR = {0,0,0,0}, aZ = {0,0,0,0}, aG = {0,0,0,0}, aI = {0,0,0,0};
                uint4 fx = *(const uint4*)(xbase + (size_t)t * 512 + rt * 256);
                short8 xv = __builtin_bit_cast(short8, fx);
#pragma unroll
                for (int kt = 0; kt < 4; ++kt) {
                    short8 av = __builtin_bit_cast(short8, f0[kt]);
                    aR = MFMA16(av, __builtin_bit_cast(short8, wv[kt]), aR, 0, 0, 0);
                    aZ = MFMA16(av, __builtin_bit_cast(short8, wv[5 + kt]), aZ, 0, 0, 0);
                    aG = MFMA16(av, __builtin_bit_cast(short8, wv[10 + kt]), aG, 0, 0, 0);
                }
                aR = MFMA16(xv, __builtin_bit_cast(short8, wv[4]), aR, 0, 0, 0);
                aZ = MFMA16(xv, __builtin_bit_cast(short8, wv[9]), aZ, 0, 0, 0);
                aI = MFMA16(xv, __builtin_bit_cast(short8, wv[14]), aI, 0, 0, 0);
#pragma unroll
                for (int i = 0; i < 4; ++i) {
                    float rg = __builtin_amdgcn_rcpf(1.f + __expf(-(aR[i] + br0)));
                    float zg = __builtin_amdgcn_rcpf(1.f + __expf(-(aZ[i] + bz0)));
                    float nn = aI[i] + bgi0 + rg * (aG[i] + bgn0);
                    float e2 = __expf(2.f * nn);
                    float ng = 1.f - 2.f * __builtin_amdgcn_rcpf(e2 + 1.f);
                    float hn = ng + zg * (hs0[rt][i] - ng);
                    hs0[rt][i] = hn;
                    int Rw = (rt << 4) + (g << 2) + i;
                    *(unsigned short*)(smem + pr + (Rw << 8) + (((hc >> 3) ^ (Rw & 15)) << 4) + ((hc & 7) << 1)) = f2h(hn);
                }
            }
            __builtin_amdgcn_sched_barrier(0);

            // ================= phase B: L1(t-1) complete =================
            if (t > 0) {
                f32x4 cR = {0,0,0,0}, cZ = {0,0,0,0}, cG = {0,0,0,0}, cI = {0,0,0,0};
                // y-part: reuse f0
#pragma unroll
                for (int kt = 0; kt < 4; ++kt) {
                    short8 av = __builtin_bit_cast(short8, f0[kt]);
                    cR = MFMA16(av, __builtin_bit_cast(short8, wv[15 + kt]), cR, 0, 0, 0);
                    cZ = MFMA16(av, __builtin_bit_cast(short8, wv[23 + kt]), cZ, 0, 0, 0);
                    cI = MFMA16(av, __builtin_bit_cast(short8, wv[35 + kt]), cI, 0, 0, 0);
                }
                // h1-part: f1 = h1(t-2), read inline (short live range)
#pragma unroll
                for (int kt = 0; kt < 4; ++kt) {
                    uint4 f1 = *(const uint4*)(smem + 16384 + pr + rowb + ((((kt << 2) | g) ^ xr) << 4));
                    short8 bv = __builtin_bit_cast(short8, f1);
                    cR = MFMA16(bv, __builtin_bit_cast(short8, wv[19 + kt]), cR, 0, 0, 0);
                    cZ = MFMA16(bv, __builtin_bit_cast(short8, wv[27 + kt]), cZ, 0, 0, 0);
                    cG = MFMA16(bv, __builtin_bit_cast(short8, wv[31 + kt]), cG, 0, 0, 0);
                }
#pragma unroll
                for (int i = 0; i < 4; ++i) {
                    float rg = __builtin_amdgcn_rcpf(1.f + __expf(-(cR[i] + br1)));
                    float zg = __builtin_amdgcn_rcpf(1.f + __expf(-(cZ[i] + bz1)));
                    float nn = cI[i] + bgi1 + rg * (cG[i] + bgn1);
                    float e2 = __expf(2.f * nn);
                    float ng = 1.f - 2.f * __builtin_amdgcn_rcpf(e2 + 1.f);
                    float hn = ng + zg * (hs1[rt][i] - ng);
                    hs1[rt][i] = hn;
                    int Rw = (rt << 4) + (g << 2) + i;
                    *(unsigned short*)(smem + 16384 + prx + (Rw << 8) + (((hc >> 3) ^ (Rw & 15)) << 4) + ((hc & 7) << 1)) = f2h(hn);
                }
            }
            __builtin_amdgcn_sched_barrier(0);
        }
        __syncthreads();
    }

#pragma unroll
    for (int rt = 0; rt < 2; ++rt)
#pragma unroll
        for (int i = 0; i < 4; ++i) {
            int Rw = (rt << 4) + (g << 2) + i;
            hidden[(size_t)(n0 + Rw) * H + hc] = hs1[rt][i];
        }
}

// ------------------------------------------------------------------ epilogue
__global__ void k_rowstats(const float* __restrict__ hidden, const float* __restrict__ GH,
                           const float* __restrict__ wv1, const float* __restrict__ cc,
                           float* __restrict__ sx, float* __restrict__ invdv)
{
    int lane = threadIdx.x & 63;
    int wv = threadIdx.x >> 6;
    int n = blockIdx.x * 4 + wv;
    float p = hidden[(size_t)n * H + lane] * wv1[lane]
            + hidden[(size_t)n * H + 64 + lane] * wv1[64 + lane];
    float g = (lane < E_) ? GH[(size_t)n * E_ + lane] : 0.f;
#pragma unroll
    for (int off = 32; off > 0; off >>= 1) {
        p += __shfl_down(p, off);
        g += __shfl_down(g, off);
    }
    if (lane == 0) {
        sx[n] = p + cc[0];
        float dv = 0.5f * g;
        invdv[n] = (dv != 0.f) ? 1.f / dv : 0.f;
    }
}

// 256 blocks x 32 rows
__global__ void k_agg(const float* __restrict__ hidden, const float* __restrict__ GH,
                      float* __restrict__ agg, float* __restrict__ de)
{
    int t = threadIdx.x;
    int nbase = blockIdx.x * 32;
    if (t < H) {
        float part[E_];
#pragma unroll
        for (int e = 0; e < E_; ++e) part[e] = 0.f;
        for (int r = 0; r < 32; ++r) {
            int n = nbase + r;
            float hv = hidden[(size_t)n * H + t];
#pragma unroll
            for (int e = 0; e < E_; ++e) part[e] += GH[(size_t)n * E_ + e] * hv;
        }
#pragma unroll
        for (int e = 0; e < E_; ++e) atomicAdd(&agg[e * H + t], part[e]);
    } else if (t < H + E_) {
        int e = t - H;
        float s = 0.f;
        for (int r = 0; r < 32; ++r) s += GH[(size_t)(nbase + r) * E_ + e];
        atomicAdd(&de[e], s);
    }
}

__global__ void k_sy(const float* __restrict__ agg, const float* __restrict__ wv2,
                     const float* __restrict__ cc, const float* __restrict__ de,
                     float* __restrict__ sy, float* __restrict__ invde)
{
    int e = threadIdx.x;
    if (e < E_) {
        float s = 0.f;
        for (int h = 0; h < H; ++h) s += agg[e * H + h] * wv2[h];
        sy[e] = s + cc[1];
        float d = de[e];
        invde[e] = (d != 0.f) ? 1.f / d : 0.f;
    }
}

// 256 blocks x 32 rows, one barrier; invdv folded into att
__global__ void k_attS(const float* __restrict__ hidden, const float* __restrict__ sx,
                       const float* __restrict__ sy, const float* __restrict__ invdv,
                       float* __restrict__ S)
{
    __shared__ float att_s[32][E_];
    __shared__ float sy_s[E_];
    int t = threadIdx.x;
    if (t < E_) sy_s[t] = sy[t];
    __syncthreads();
    int nbase = blockIdx.x * 32;
    if (t < 32) {
        int n = nbase + t;
        float sxn = sx[n];
        float vv[E_];
        float m = -1e30f;
#pragma unroll
        for (int e = 0; e < E_; ++e) {
            float v = sxn + sy_s[e];
            v = (v >= 0.f) ? v : 0.01f * v;
            vv[e] = v;
            m = fmaxf(m, v);
        }
        float ss = 0.f;
#pragma unroll
        for (int e = 0; e < E_; ++e) { vv[e] = __expf(vv[e] - m); ss += vv[e]; }
        float sc = invdv[n] / ss;
#pragma unroll
        for (int e = 0; e < E_; ++e) att_s[t][e] = vv[e] * sc;
    }
    __syncthreads();
    if (t < H) {
        float part[E_];
#pragma unroll
        for (int e = 0; e < E_; ++e) part[e] = 0.f;
        for (int r = 0; r < 32; ++r) {
            float hv = hidden[(size_t)(nbase + r) * H + t];
#pragma unroll
            for (int e = 0; e < E_; ++e) part[e] += att_s[r][e] * hv;
        }
#pragma unroll
        for (int e = 0; e < E_; ++e) atomicAdd(&S[e * H + t], part[e]);
    }
}

// 256 blocks x 256 threads; wave-per-row, 8 rows per wave
__global__ __launch_bounds__(256) void k_final(
    const float* __restrict__ hidden, const float* __restrict__ sx,
    const float* __restrict__ sy, const float* __restrict__ invdv,
    const float* __restrict__ invde, const float* __restrict__ S,
    const float* __restrict__ WfcT, const float* __restrict__ bfc,
    const float* __restrict__ Wout, const float* __restrict__ bout,
    float* __restrict__ out)
{
    __shared__ float S_s[E_ * H];
    __shared__ float sy_s[E_], ide_s[E_];
    __shared__ float nh[4][H];
    int t = threadIdx.x;
    for (int i = t; i < E_ * H; i += 256) S_s[i] = S[i];
    if (t < E_) { sy_s[t] = sy[t]; ide_s[t] = invde[t]; }
    __syncthreads();
    int wv = t >> 6, lane = t & 63;
    float wouta = Wout[lane], woutb = Wout[64 + lane];
    float bfca = bfc[lane], bfcb = bfc[64 + lane];
    float boutv = bout[0];
    for (int it = 0; it < 8; ++it) {
        int n = blockIdx.x * 32 + it * 4 + wv;
        float sxn = sx[n];
        float idv = invdv[n];
        float vv[E_];
        float m = -1e30f;
#pragma unroll
        for (int e = 0; e < E_; ++e) {
            float v = sxn + sy_s[e];
            v = (v >= 0.f) ? v : 0.01f * v;
            vv[e] = v;
            m = fmaxf(m, v);
        }
        float ss = 0.f;
#pragma unroll
        for (int e = 0; e < E_; ++e) { vv[e] = __expf(vv[e] - m); ss += vv[e]; }
        float sc = idv / ss;
        float a0 = hidden[(size_t)n * H + lane];
        float a1 = hidden[(size_t)n * H + 64 + lane];
#pragma unroll
        for (int e = 0; e < E_; ++e) {
            float wgt = vv[e] * sc * ide_s[e];
            a0 += wgt * S_s[e * H + lane];
            a1 += wgt * S_s[e * H + 64 + lane];
        }
        nh[wv][lane] = a0;
        nh[wv][64 + lane] = a1;
        __syncthreads();
        float f0 = bfca, f1 = bfcb;
        for (int h = 0; h < H; h += 4) {
            float4 nv = *(const float4*)&nh[wv][h];
            f0 += nv.x * WfcT[(h + 0) * H + lane] + nv.y * WfcT[(h + 1) * H + lane]
                + nv.z * WfcT[(h + 2) * H + lane] + nv.w * WfcT[(h + 3) * H + lane];
            f1 += nv.x * WfcT[(h + 0) * H + 64 + lane] + nv.y * WfcT[(h + 1) * H + 64 + lane]
                + nv.z * WfcT[(h + 2) * H + 64 + lane] + nv.w * WfcT[(h + 3) * H + 64 + lane];
        }
        f0 = (f0 >= 0.f) ? f0 : 0.01f * f0;
        f1 = (f1 >= 0.f) ? f1 : 0.01f * f1;
        float op = f0 * wouta + f1 * woutb;
#pragma unroll
        for (int off = 32; off > 0; off >>= 1) op += __shfl_down(op, off);
        if (lane == 0) out[n] = op + boutv;
        __syncthreads();
    }
}

// ------------------------------------------------------------------ launcher
extern "C" void kernel_launch(void* const* d_in, const int* in_sizes, int n_in,
                              void* d_out, int out_size, void* d_ws, size_t ws_size,
                              hipStream_t stream)
{
    const float* x    = (const float*)d_in[0];
    const float* GH   = (const float*)d_in[1];
    const float* Wih0 = (const float*)d_in[2];
    const float* Whh0 = (const float*)d_in[3];
    const float* bih0 = (const float*)d_in[4];
    const float* bhh0 = (const float*)d_in[5];
    const float* Wih1 = (const float*)d_in[6];
    const float* Whh1 = (const float*)d_in[7];
    const float* bih1 = (const float*)d_in[8];
    const float* bhh1 = (const float*)d_in[9];
    const float* Wt   = (const float*)d_in[10];
    const float* bt   = (const float*)d_in[11];
    const float* a    = (const float*)d_in[12];
    const float* Wfc  = (const float*)d_in[13];
    const float* bfc  = (const float*)d_in[14];
    const float* Wout = (const float*)d_in[15];
    const float* bout = (const float*)d_in[16];

    float* ws    = (float*)d_ws;
    uint4* pack  = (uint4*)(ws + OFF_PACK);
    float* WfcT  = ws + OFF_WFCT;
    float* hid   = ws + OFF_HID;
    float* sx    = ws + OFF_SX;
    float* idv   = ws + OFF_IDV;
    float* agg   = ws + OFF_AGG;
    float* de    = ws + OFF_DE;
    float* S     = ws + OFF_S;
    float* ide   = ws + OFF_IDE;
    float* sy    = ws + OFF_SY;
    float* cc    = ws + OFF_CC;
    float* wv1   = ws + OFF_WV1;
    float* wv2   = ws + OFF_WV2;

    k_pack<<<78, 256, 0, stream>>>(Wih0, Whh0, Wih1, Whh1, pack);
    k_prep_fc<<<64, 256, 0, stream>>>(Wfc, WfcT);
    k_prep_wv<<<1, 128, 0, stream>>>(Wt, bt, a, wv1, wv2, cc);
    k_zero<<<31, 256, 0, stream>>>(agg);

    const size_t lds_bytes = 65024;
    (void)hipFuncSetAttribute((const void*)k_gru,
                              hipFuncAttributeMaxDynamicSharedMemorySize,
                              (int)lds_bytes);
    k_gru<<<256, 512, lds_bytes, stream>>>(x, pack, bih0, bhh0, bih1, bhh1, hid);

    k_rowstats<<<2048, 256, 0, stream>>>(hid, GH, wv1, cc, sx, idv);
    k_agg<<<256, 256, 0, stream>>>(hid, GH, agg, de);
    k_sy<<<1, 64, 0, stream>>>(agg, wv2, cc, de, sy, ide);
    k_attS<<<256, 256, 0, stream>>>(hid, sx, sy, idv, S);
    k_final<<<256, 256, 0, stream>>>(hid, sx, sy, idv, ide, S, WfcT, bfc,
                                     Wout, bout, (float*)d_out);
}